// Round 13
// baseline (265.944 us; speedup 1.0000x reference)
//
#include <hip/hip_runtime.h>
#include <hip/hip_fp16.h>

#define N_NODES 200000
#define N_EDGES 6400000
#define F_IN 34
#define F_HID 10
#define F_OUT 4
#define HPAD 12              // fb path only: 48B fp32 rows
#define BINS 782             // dst buckets
#define NPB 256              // nodes per bucket: 782*256 = 200192 >= N
#define CHUNK 16384
#define BLK1 ((N_EDGES + CHUNK - 1) / CHUNK)    // 391
#define SCAN_L (BINS * BLK1)                    // 305762
#define NA ((SCAN_L + 511) / 512)               // 598 (<= 1024 for scanB)
#define ACCP 11              // fallback-arm LDS acc padding
#define SORT_CAP 8960        // 35KB LDS in p5 -> 53KB total -> 3 blocks/CU (8.6 sigma margin)
#define SBINS 4096           // p5 composite key: (ld<<4) | (src>>14)

typedef float floatx4 __attribute__((ext_vector_type(4)));   // nontemporal-store-compatible

// ---------------------------------------------------------------- helpers
__device__ __forceinline__ float2 up2(unsigned u) {
    __half2 h = *reinterpret_cast<const __half2*>(&u);
    return __half22float2(h);
}

// ---------------------------------------------------------------- mode detect
// int64 edge_index => every odd 32-bit word is zero (values < 2^31).
__global__ void detect_mode_kernel(const int* __restrict__ ei, int* __restrict__ mode) {
    int t = threadIdx.x;                 // 64 threads
    int v = ei[2 * t + 1];
    unsigned long long b = __ballot(v != 0);
    if (t == 0) *mode = (b == 0ull) ? 1 : 0;
}

__device__ __forceinline__ int load_idx(const int* ei, long long elem, int mode) {
    return mode ? ei[2 * elem] : ei[elem];
}

// ---------------------------------------------------------------- pass 1: bucket counts (LDS hist)
__global__ void p1_count_kernel(const int* __restrict__ ei,
                                const int* __restrict__ mode_p,
                                int* __restrict__ bcnt) {
    __shared__ int hist[BINS];
    const int mode = *mode_p;
    int t = threadIdx.x;
    for (int j = t; j < BINS; j += blockDim.x) hist[j] = 0;
    __syncthreads();

    long long base = (long long)blockIdx.x * CHUNK;
    for (int k = t; k < CHUNK; k += blockDim.x) {
        long long e = base + k;
        if (e >= N_EDGES) break;
        int d = load_idx(ei, (long long)N_EDGES + e, mode);
        if ((unsigned)d < (unsigned)N_NODES) atomicAdd(&hist[d >> 8], 1);
    }
    __syncthreads();
    for (int j = t; j < BINS; j += blockDim.x)
        bcnt[j * BLK1 + blockIdx.x] = hist[j];   // bin-major
}

// ---------------------------------------------------------------- scan A: per-512-block sums
__global__ void scanA_kernel(const int* __restrict__ src, int* __restrict__ bsum) {
    __shared__ int s[512];
    int t = threadIdx.x;
    int i = blockIdx.x * 512 + t;
    s[t] = (i < SCAN_L) ? src[i] : 0;
    __syncthreads();
    for (int o = 256; o > 0; o >>= 1) {
        if (t < o) s[t] += s[t + o];
        __syncthreads();
    }
    if (t == 0) bsum[blockIdx.x] = s[0];
}

// ---------------------------------------------------------------- scan B: exclusive scan of NA block sums
__global__ void scanB_kernel(int* __restrict__ bsum, int* __restrict__ total) {
    __shared__ int s[1024];
    int t = threadIdx.x;
    int v = (t < NA) ? bsum[t] : 0;
    s[t] = v;
    __syncthreads();
    for (int o = 1; o < 1024; o <<= 1) {
        int u = (t >= o) ? s[t - o] : 0;
        __syncthreads();
        s[t] += u;
        __syncthreads();
    }
    if (t < NA) bsum[t] = s[t] - v;             // exclusive block offset
    if (t == 1023) *total = s[t];
}

// ---------------------------------------------------------------- scan C: produce boff (512-granule)
__global__ void scanC_kernel(const int* __restrict__ src,
                             const int* __restrict__ bsum,
                             int* __restrict__ dst) {
    __shared__ int s[512];
    int t = threadIdx.x;
    int i = blockIdx.x * 512 + t;
    int v = (i < SCAN_L) ? src[i] : 0;
    s[t] = v;
    __syncthreads();
    for (int o = 1; o < 512; o <<= 1) {
        int u = (t >= o) ? s[t - o] : 0;
        __syncthreads();
        s[t] += u;
        __syncthreads();
    }
    if (i < SCAN_L) dst[i] = bsum[blockIdx.x] + s[t] - v;  // exclusive prefix
}

// ---------------------------------------------------------------- pass 3: LDS-staged fill.
__global__ void __launch_bounds__(512, 4)
p3_fill_kernel(const int* __restrict__ ei,
               const int* __restrict__ mode_p,
               const int* __restrict__ bcnt,
               const int* __restrict__ boff,
               int* __restrict__ ebuf) {
    __shared__ int buf[CHUNK];          // 64 KB
    __shared__ int hist[BINS];
    __shared__ int lstart[BINS];
    __shared__ int cur[BINS];

    const int mode = *mode_p;
    int t = threadIdx.x;
    int blk = blockIdx.x;

    for (int j = t; j < BINS; j += 512) hist[j] = bcnt[j * BLK1 + blk];
    __syncthreads();

    // exclusive scan of hist[0..BINS) by wave 0: 13 bins/lane (64*13=832 >= 782)
    if (t < 64) {
        int base = t * 13;
        int run = 0;
        int loc[13];
#pragma unroll
        for (int u = 0; u < 13; ++u) {
            int idx = base + u;
            int v = (idx < BINS) ? hist[idx] : 0;
            loc[u] = run;
            run += v;
        }
        int inc = run;
        for (int o = 1; o < 64; o <<= 1) {
            int up = __shfl_up(inc, o);
            if (t >= o) inc += up;
        }
        int excl = inc - run;
#pragma unroll
        for (int u = 0; u < 13; ++u) {
            int idx = base + u;
            if (idx < BINS) { lstart[idx] = excl + loc[u]; cur[idx] = excl + loc[u]; }
        }
    }
    __syncthreads();

    // pass B: read edges, place into buf at sorted local position
    long long base = (long long)blk * CHUNK;
    int nthis = (int)(((long long)N_EDGES - base < (long long)CHUNK)
                      ? ((long long)N_EDGES - base) : (long long)CHUNK);
    for (int k = t; k < nthis; k += 512) {
        long long e = base + k;
        int d = load_idx(ei, (long long)N_EDGES + e, mode);
        if ((unsigned)d >= (unsigned)N_NODES) continue;
        int s = load_idx(ei, e, mode);
        s = min(max(s, 0), N_NODES - 1);         // memory-safety clamp (input always valid)
        int bin = d >> 8;
        int ld = d & 255;
        int pos = atomicAdd(&cur[bin], 1);       // local position in sorted order
        buf[pos] = s | (ld << 18);               // src:18 bits | local_dst:8 bits
    }
    __syncthreads();

    // write-out: wave w handles bins w, w+8, ... — contiguous coalesced bursts
    int wave = t >> 6, lane = t & 63;
    for (int bb = wave; bb < BINS; bb += 8) {
        int ls = lstart[bb];
        int ncnt = cur[bb] - ls;
        int gb = boff[bb * BLK1 + blk];
        for (int k = lane; k < ncnt; k += 64)
            ebuf[gb + k] = buf[ls + k];
    }
}

// ---------------------------------------------------------------- pass 5: per-bucket counting
// sort by COMPOSITE KEY (local_dst, src>>14); nodeoff/deg from bin scan; dis -> disf.
__global__ void p5_sort_kernel(int* __restrict__ ebuf,
                               const int* __restrict__ boff,
                               const int* __restrict__ total,
                               float* __restrict__ disf,
                               int* __restrict__ nodeoff,
                               int* __restrict__ flag) {
    __shared__ int buf[SORT_CAP];       // 35 KB
    __shared__ int bins[SBINS];         // 16 KB: counts -> absolute excl scan -> cursors
    __shared__ int part[512];

    int b = blockIdx.x;
    int t = threadIdx.x;
    for (int j = t; j < SBINS; j += 512) bins[j] = 0;
    __syncthreads();

    int start = boff[b * BLK1];
    int end = (b < BINS - 1) ? boff[(b + 1) * BLK1] : *total;
    int n = end - start;
    bool fit = (n <= SORT_CAP);

    for (int k = t; k < n; k += 512) {
        int v = __builtin_nontemporal_load(ebuf + start + k);
        int key = ((((unsigned)v) >> 18) << 4) | ((v & 0x3FFFF) >> 14);
        atomicAdd(&bins[key], 1);
        if (fit) buf[k] = v;
    }
    __syncthreads();

    // blocked exclusive scan of bins[0..SBINS) -> ABSOLUTE positions (+start)
    int base = t * 8;
    int loc[8];
    int run = 0;
#pragma unroll
    for (int u = 0; u < 8; ++u) { loc[u] = run; run += bins[base + u]; }
    part[t] = run;
    __syncthreads();
    for (int o = 1; o < 512; o <<= 1) {
        int u = (t >= o) ? part[t - o] : 0;
        __syncthreads();
        part[t] += u;
        __syncthreads();
    }
    int excl = part[t] - run;
#pragma unroll
    for (int u = 0; u < 8; ++u) bins[base + u] = start + excl + loc[u];
    __syncthreads();

    // nodeoff + dis (read bins BEFORE cursors get bumped)
    if (t < NPB) {
        int ns = bins[t * 16];
        nodeoff[b * NPB + t] = ns;
        int ne = (t < NPB - 1) ? bins[(t + 1) * 16] : end;
        int i = b * NPB + t;
        if (i < N_NODES) disf[i] = rsqrtf((float)((ne - ns) + 1));   // +1 self-loop
    }
    if (b == BINS - 1 && t == 0) nodeoff[BINS * NPB] = end;
    if (t == 0) flag[b] = fit ? 1 : 0;
    __syncthreads();

    if (!fit) return;
    // scatter back in (ld, src-window) order; bins[] cursors are ABSOLUTE
    for (int k = t; k < n; k += 512) {
        int v = buf[k];
        int key = ((((unsigned)v) >> 18) << 4) | ((v & 0x3FFFF) >> 14);
        int pos = atomicAdd(&bins[key], 1);
        ebuf[pos] = v;
    }
}

// ---------------------------------------------------------------- init2: h = (x @ W) * dis,
// split SoA: hpkA = 8 fp16 (16B, 3.2MB), hpkB = 2 fp16 (4B, 0.8MB) -> 4.0MB gather set.
__global__ void init2_kernel(const float* __restrict__ x,
                             const float* __restrict__ Wg,
                             const float* __restrict__ disf,
                             uint4* __restrict__ hpkA,
                             unsigned* __restrict__ hpkB) {
    __shared__ float Ws[F_IN * F_HID];
    for (int t = threadIdx.x; t < F_IN * F_HID; t += blockDim.x) Ws[t] = Wg[t];
    __syncthreads();

    int i = blockIdx.x * blockDim.x + threadIdx.x;
    if (i >= N_NODES) return;

    float acc[F_HID];
#pragma unroll
    for (int f = 0; f < F_HID; ++f) acc[f] = 0.0f;

    const float* xr = x + (long long)i * F_IN;
#pragma unroll
    for (int k = 0; k < F_IN; ++k) {
        float xv = xr[k];
#pragma unroll
        for (int f = 0; f < F_HID; ++f) acc[f] += xv * Ws[k * F_HID + f];
    }

    float di = disf[i];
    unsigned pk[5];
#pragma unroll
    for (int k = 0; k < 5; ++k) {
        __half lo = __float2half(acc[2 * k] * di);
        __half hi = __float2half(acc[2 * k + 1] * di);
        pk[k] = ((unsigned)__half_as_ushort(hi) << 16) | (unsigned)__half_as_ushort(lo);
    }
    hpkA[i] = make_uint4(pk[0], pk[1], pk[2], pk[3]);
    hpkB[i] = pk[4];
}

// ---------------------------------------------------------------- pass 4b: per-node register
// gather-accumulate (NO atomics). 2 blocks/bucket, 128 nodes/block, 4 threads/node,
// batch-4, shfl_xor(1)+(2) combine. Gather set = 4.0MB (L2-resident); nt on streams.
__global__ void __launch_bounds__(512, 8)
p4b_acc_kernel(const int* __restrict__ ebuf,
               const int* __restrict__ nodeoff,
               const int* __restrict__ flag,
               const uint4* __restrict__ hpkA,
               const unsigned* __restrict__ hpkB,
               const float* __restrict__ disf,
               const float* __restrict__ b_gcn,
               const float* __restrict__ W_fc,
               const float* __restrict__ b_fc,
               float* __restrict__ out) {
    __shared__ float accs[128 * ACCP];   // fallback arm only
    __shared__ float Wfs[F_HID * F_OUT];
    __shared__ float bfs[F_OUT];
    __shared__ float bgs[F_HID];

    int bb = blockIdx.x >> 1;            // bucket
    int half = blockIdx.x & 1;           // which 128-node half
    int t = threadIdx.x;                 // 0..511
    int jl = t >> 2;                     // local node 0..127
    int par = t & 3;                     // parity within node quad
    if (t < F_HID * F_OUT) Wfs[t] = W_fc[t];
    if (t < F_OUT) bfs[t] = b_fc[t];
    if (t < F_HID) bgs[t] = b_gcn[t];
    __syncthreads();

    float* hidden = out;                               // [N, F_HID]
    floatx4* o24 = reinterpret_cast<floatx4*>(out + (long long)N_NODES * F_HID);

    int i = bb * NPB + half * 128 + jl;
    bool valid = (i < N_NODES);
    float acc[F_HID];
#pragma unroll
    for (int f = 0; f < F_HID; ++f) acc[f] = 0.0f;

    if (flag[bb]) {
        // ---------- fast arm: (ld, src-window)-sorted, register accumulation ----------
        int rs = valid ? nodeoff[i] : 0;
        int re = valid ? nodeoff[i + 1] : 0;
        for (int k0 = rs + par; k0 < re; k0 += 16) {   // this thread: k0, k0+4, k0+8, k0+12
            unsigned v[4]; uint4 qa[4]; unsigned qb[4];
#pragma unroll
            for (int u = 0; u < 4; ++u)
                v[u] = (unsigned)__builtin_nontemporal_load(ebuf + min(k0 + 4 * u, re - 1));
#pragma unroll
            for (int u = 0; u < 4; ++u) {
                int s = v[u] & 0x3FFFF;
                qa[u] = hpkA[s];
                qb[u] = hpkB[s];
            }
#pragma unroll
            for (int u = 0; u < 4; ++u) {
                if (k0 + 4 * u < re) {
                    float2 f01 = up2(qa[u].x), f23 = up2(qa[u].y);
                    float2 f45 = up2(qa[u].z), f67 = up2(qa[u].w);
                    float2 f89 = up2(qb[u]);
                    acc[0] += f01.x; acc[1] += f01.y;
                    acc[2] += f23.x; acc[3] += f23.y;
                    acc[4] += f45.x; acc[5] += f45.y;
                    acc[6] += f67.x; acc[7] += f67.y;
                    acc[8] += f89.x; acc[9] += f89.y;
                }
            }
        }
    } else {
        // ---------- fallback arm: unsorted bucket, LDS atomics (never taken for valid input) ----
        for (int j = t; j < 128 * ACCP; j += blockDim.x) accs[j] = 0.0f;
        __syncthreads();
        int start = nodeoff[bb * NPB];
        int end = (bb < BINS - 1) ? nodeoff[(bb + 1) * NPB] : nodeoff[BINS * NPB];
        for (int e = start + t; e < end; e += blockDim.x) {
            unsigned v = (unsigned)ebuf[e];
            int s = v & 0x3FFFF;
            int ld = v >> 18;
            if ((ld >> 7) != half) continue;           // only this block's half
            uint4 qa = hpkA[s];
            unsigned qb = hpkB[s];
            float2 f01 = up2(qa.x), f23 = up2(qa.y), f45 = up2(qa.z), f67 = up2(qa.w), f89 = up2(qb);
            float* a = &accs[(ld - half * 128) * ACCP];
            atomicAdd(a + 0, f01.x); atomicAdd(a + 1, f01.y);
            atomicAdd(a + 2, f23.x); atomicAdd(a + 3, f23.y);
            atomicAdd(a + 4, f45.x); atomicAdd(a + 5, f45.y);
            atomicAdd(a + 6, f67.x); atomicAdd(a + 7, f67.y);
            atomicAdd(a + 8, f89.x); atomicAdd(a + 9, f89.y);
        }
        __syncthreads();
        if (par == 0) {                  // one lane per node takes the LDS sum; others stay 0
#pragma unroll
            for (int f = 0; f < F_HID; ++f) acc[f] = accs[jl * ACCP + f];
        }
    }

    // quad-combine: acc[node] = sum of 4 lanes
#pragma unroll
    for (int f = 0; f < F_HID; ++f) {
        acc[f] += __shfl_xor(acc[f], 1);
        acc[f] += __shfl_xor(acc[f], 2);
    }

    if (!valid || par) return;

    uint4 qa = hpkA[i];
    unsigned qb = hpkB[i];
    float di = disf[i];
    float2 f01 = up2(qa.x), f23 = up2(qa.y), f45 = up2(qa.z), f67 = up2(qa.w), f89 = up2(qb);
    float hp[F_HID] = {f01.x, f01.y, f23.x, f23.y, f45.x, f45.y, f67.x, f67.y, f89.x, f89.y};

    float hv[F_HID];
#pragma unroll
    for (int f = 0; f < F_HID; ++f) {
        hv[f] = (acc[f] + hp[f]) * di + bgs[f];    // (sum_nbrs h' + h'[i]) * dis[i] + b
        __builtin_nontemporal_store(hv[f], hidden + (long long)i * F_HID + f);
    }
    floatx4 o;
#pragma unroll
    for (int jj = 0; jj < F_OUT; ++jj) {
        float vv = bfs[jj];
#pragma unroll
        for (int f = 0; f < F_HID; ++f) vv += hv[f] * Wfs[f * F_OUT + jj];
        o[jj] = fmaxf(vv, 0.0f);
    }
    __builtin_nontemporal_store(o, o24 + i);
}

// ================================================================ FALLBACK (atomic scatter, small ws)
__global__ void fb_init_kernel(const float* __restrict__ x, const float* __restrict__ Wg,
                               float* __restrict__ hpad, float* __restrict__ deg,
                               float* __restrict__ hidden) {
    __shared__ float Ws[F_IN * F_HID];
    for (int t = threadIdx.x; t < F_IN * F_HID; t += blockDim.x) Ws[t] = Wg[t];
    __syncthreads();
    int i = blockIdx.x * blockDim.x + threadIdx.x;
    if (i >= N_NODES) return;
    float acc[F_HID];
#pragma unroll
    for (int f = 0; f < F_HID; ++f) acc[f] = 0.0f;
    const float* xr = x + (long long)i * F_IN;
#pragma unroll
    for (int k = 0; k < F_IN; ++k) {
        float xv = xr[k];
#pragma unroll
        for (int f = 0; f < F_HID; ++f) acc[f] += xv * Ws[k * F_HID + f];
    }
    float* hr = hpad + (long long)i * HPAD;
#pragma unroll
    for (int f = 0; f < F_HID; ++f) hr[f] = acc[f];
    hr[10] = 0.0f; hr[11] = 0.0f;
    deg[i] = 1.0f;
    float* hd = hidden + (long long)i * F_HID;
#pragma unroll
    for (int f = 0; f < F_HID; ++f) hd[f] = 0.0f;
}

__global__ void fb_deg_kernel(const int* __restrict__ ei, const int* __restrict__ mode_p,
                              float* __restrict__ deg) {
    const int mode = *mode_p;
    long long e = (long long)blockIdx.x * blockDim.x + threadIdx.x;
    if (e >= N_EDGES) return;
    int d = load_idx(ei, (long long)N_EDGES + e, mode);
    if ((unsigned)d < (unsigned)N_NODES) atomicAdd(&deg[d], 1.0f);
}

__global__ void fb_scatter_kernel(const int* __restrict__ ei, const int* __restrict__ mode_p,
                                  const float* __restrict__ hpad, const float* __restrict__ deg,
                                  float* __restrict__ hidden) {
    const int mode = *mode_p;
    long long e = (long long)blockIdx.x * blockDim.x + threadIdx.x;
    if (e >= N_EDGES) return;
    int s = load_idx(ei, e, mode);
    int d = load_idx(ei, (long long)N_EDGES + e, mode);
    if ((unsigned)s >= (unsigned)N_NODES || (unsigned)d >= (unsigned)N_NODES) return;
    float norm = rsqrtf(deg[s]) * rsqrtf(deg[d]);
    const float4* h4 = reinterpret_cast<const float4*>(hpad + (long long)s * HPAD);
    float4 a = h4[0]; float4 b = h4[1]; float4 c = h4[2];
    float* o = hidden + (long long)d * F_HID;
    atomicAdd(o + 0, a.x * norm); atomicAdd(o + 1, a.y * norm);
    atomicAdd(o + 2, a.z * norm); atomicAdd(o + 3, a.w * norm);
    atomicAdd(o + 4, b.x * norm); atomicAdd(o + 5, b.y * norm);
    atomicAdd(o + 6, b.z * norm); atomicAdd(o + 7, b.w * norm);
    atomicAdd(o + 8, c.x * norm); atomicAdd(o + 9, c.y * norm);
}

__global__ void fb_finalize_kernel(const float* __restrict__ hpad, const float* __restrict__ deg,
                                   const float* __restrict__ b_gcn, const float* __restrict__ W_fc,
                                   const float* __restrict__ b_fc, float* __restrict__ out) {
    __shared__ float Wf[F_HID * F_OUT];
    __shared__ float bf_s[F_OUT];
    __shared__ float bg_s[F_HID];
    for (int t = threadIdx.x; t < F_HID * F_OUT; t += blockDim.x) Wf[t] = W_fc[t];
    if (threadIdx.x < F_OUT) bf_s[threadIdx.x] = b_fc[threadIdx.x];
    if (threadIdx.x < F_HID) bg_s[threadIdx.x] = b_gcn[threadIdx.x];
    __syncthreads();
    int i = blockIdx.x * blockDim.x + threadIdx.x;
    if (i >= N_NODES) return;
    float* hidden = out;
    float* o2 = out + (long long)N_NODES * F_HID;
    float inv = 1.0f / deg[i];
    const float* hr = hpad + (long long)i * HPAD;
    float* hd = hidden + (long long)i * F_HID;
    float hv[F_HID];
#pragma unroll
    for (int f = 0; f < F_HID; ++f) {
        hv[f] = hd[f] + hr[f] * inv + bg_s[f];
        hd[f] = hv[f];
    }
#pragma unroll
    for (int j = 0; j < F_OUT; ++j) {
        float o = bf_s[j];
#pragma unroll
        for (int f = 0; f < F_HID; ++f) o += hv[f] * Wf[f * F_OUT + j];
        o2[(long long)i * F_OUT + j] = fmaxf(o, 0.0f);
    }
}

// ---------------------------------------------------------------- launch
extern "C" void kernel_launch(void* const* d_in, const int* in_sizes, int n_in,
                              void* d_out, int out_size, void* d_ws, size_t ws_size,
                              hipStream_t stream) {
    const float* x  = (const float*)d_in[0];
    const int*   ei = (const int*)d_in[1];
    const float* Wg = (const float*)d_in[2];
    const float* bg = (const float*)d_in[3];
    const float* Wf = (const float*)d_in[4];
    const float* bf = (const float*)d_in[5];
    float* out = (float*)d_out;

    const int nblk_node = (N_NODES + 255) / 256;     // 782

    // main ws layout (~34 MB)
    uint4*    hpkA    = (uint4*)d_ws;                               // N (16B) = 3.2MB
    unsigned* hpkB    = (unsigned*)(hpkA + N_NODES);                // N (4B)  = 0.8MB
    float*    disf    = (float*)(hpkB + N_NODES);                   // N
    int*      bcnt    = (int*)(disf + N_NODES);                     // SCAN_L
    int*      boff    = bcnt + SCAN_L;                              // SCAN_L
    int*      bsum    = boff + SCAN_L;                              // 1024 (NA=598 used)
    int*      total   = bsum + 1024;                                // 1
    int*      nodeoff = total + 1;                                  // BINS*NPB+1
    int*      flag    = nodeoff + BINS * NPB + 1;                   // BINS
    int*      ebuf    = flag + BINS;                                // N_EDGES
    int*      mode    = ebuf + N_EDGES;                             // 1
    size_t need = (size_t)((char*)(mode + 1) - (char*)d_ws);

    if (ws_size >= need) {
        detect_mode_kernel<<<1, 64, 0, stream>>>(ei, mode);
        p1_count_kernel<<<BLK1, 512, 0, stream>>>(ei, mode, bcnt);
        scanA_kernel<<<NA, 512, 0, stream>>>(bcnt, bsum);
        scanB_kernel<<<1, 1024, 0, stream>>>(bsum, total);
        scanC_kernel<<<NA, 512, 0, stream>>>(bcnt, bsum, boff);
        p3_fill_kernel<<<BLK1, 512, 0, stream>>>(ei, mode, bcnt, boff, ebuf);
        p5_sort_kernel<<<BINS, 512, 0, stream>>>(ebuf, boff, total, disf, nodeoff, flag);
        init2_kernel<<<nblk_node, 256, 0, stream>>>(x, Wg, disf, hpkA, hpkB);
        p4b_acc_kernel<<<BINS * 2, 512, 0, stream>>>(ebuf, nodeoff, flag, hpkA, hpkB, disf,
                                                     bg, Wf, bf, out);
    } else {
        // fallback: atomic scatter (~10.4 MB)
        float* hpad  = (float*)d_ws;
        float* degf  = hpad + (size_t)N_NODES * HPAD;
        int*   mode2 = (int*)(degf + N_NODES);
        const int nblk_edge = (N_EDGES + 255) / 256;
        detect_mode_kernel<<<1, 64, 0, stream>>>(ei, mode2);
        fb_init_kernel<<<nblk_node, 256, 0, stream>>>(x, Wg, hpad, degf, out);
        fb_deg_kernel<<<nblk_edge, 256, 0, stream>>>(ei, mode2, degf);
        fb_scatter_kernel<<<nblk_edge, 256, 0, stream>>>(ei, mode2, hpad, degf, out);
        fb_finalize_kernel<<<nblk_node, 256, 0, stream>>>(hpad, degf, bg, Wf, bf, out);
    }
}

// Round 14
// 249.018 us; speedup vs baseline: 1.0680x; 1.0680x over previous
//
#include <hip/hip_runtime.h>
#include <hip/hip_fp16.h>

#define N_NODES 200000
#define N_EDGES 6400000
#define F_IN 34
#define F_HID 10
#define F_OUT 4
#define HPAD 12              // fb path only: 48B fp32 rows
#define BINS 782             // dst buckets
#define NPB 256              // nodes per bucket: 782*256 = 200192 >= N
#define CHUNK 16384
#define BLK1 ((N_EDGES + CHUNK - 1) / CHUNK)    // 391
#define SCAN_L (BINS * BLK1)                    // 305762
#define NA ((SCAN_L + 511) / 512)               // 598 (<= 1024 for scanB)
#define ACCP 11              // fallback-arm LDS acc padding
#define SORT_CAP 8960        // 35KB LDS in p5 -> 3 blocks/CU (8.6 sigma margin)
#define SBINS 4096           // p5 composite key: (ld<<4) | (src>>14)

typedef float floatx4 __attribute__((ext_vector_type(4)));     // nontemporal-store-compatible
typedef unsigned uintx4 __attribute__((ext_vector_type(4)));
typedef unsigned uintx4_a4 __attribute__((ext_vector_type(4), aligned(4)));  // 4B-aligned 16B load

// ---------------------------------------------------------------- helpers
__device__ __forceinline__ float2 up2(unsigned u) {
    __half2 h = *reinterpret_cast<const __half2*>(&u);
    return __half22float2(h);
}

// ---------------------------------------------------------------- mode detect
// int64 edge_index => every odd 32-bit word is zero (values < 2^31).
__global__ void detect_mode_kernel(const int* __restrict__ ei, int* __restrict__ mode) {
    int t = threadIdx.x;                 // 64 threads
    int v = ei[2 * t + 1];
    unsigned long long b = __ballot(v != 0);
    if (t == 0) *mode = (b == 0ull) ? 1 : 0;
}

__device__ __forceinline__ int load_idx(const int* ei, long long elem, int mode) {
    return mode ? ei[2 * elem] : ei[elem];
}

// ---------------------------------------------------------------- pass 1: bucket counts (LDS hist)
__global__ void p1_count_kernel(const int* __restrict__ ei,
                                const int* __restrict__ mode_p,
                                int* __restrict__ bcnt) {
    __shared__ int hist[BINS];
    const int mode = *mode_p;
    int t = threadIdx.x;
    for (int j = t; j < BINS; j += blockDim.x) hist[j] = 0;
    __syncthreads();

    long long base = (long long)blockIdx.x * CHUNK;
    for (int k = t; k < CHUNK; k += blockDim.x) {
        long long e = base + k;
        if (e >= N_EDGES) break;
        int d = load_idx(ei, (long long)N_EDGES + e, mode);
        if ((unsigned)d < (unsigned)N_NODES) atomicAdd(&hist[d >> 8], 1);
    }
    __syncthreads();
    for (int j = t; j < BINS; j += blockDim.x)
        bcnt[j * BLK1 + blockIdx.x] = hist[j];   // bin-major
}

// ---------------------------------------------------------------- scan A: per-512-block sums
__global__ void scanA_kernel(const int* __restrict__ src, int* __restrict__ bsum) {
    __shared__ int s[512];
    int t = threadIdx.x;
    int i = blockIdx.x * 512 + t;
    s[t] = (i < SCAN_L) ? src[i] : 0;
    __syncthreads();
    for (int o = 256; o > 0; o >>= 1) {
        if (t < o) s[t] += s[t + o];
        __syncthreads();
    }
    if (t == 0) bsum[blockIdx.x] = s[0];
}

// ---------------------------------------------------------------- scan B: exclusive scan of NA block sums
__global__ void scanB_kernel(int* __restrict__ bsum, int* __restrict__ total) {
    __shared__ int s[1024];
    int t = threadIdx.x;
    int v = (t < NA) ? bsum[t] : 0;
    s[t] = v;
    __syncthreads();
    for (int o = 1; o < 1024; o <<= 1) {
        int u = (t >= o) ? s[t - o] : 0;
        __syncthreads();
        s[t] += u;
        __syncthreads();
    }
    if (t < NA) bsum[t] = s[t] - v;             // exclusive block offset
    if (t == 1023) *total = s[t];
}

// ---------------------------------------------------------------- scan C: produce boff (512-granule)
__global__ void scanC_kernel(const int* __restrict__ src,
                             const int* __restrict__ bsum,
                             int* __restrict__ dst) {
    __shared__ int s[512];
    int t = threadIdx.x;
    int i = blockIdx.x * 512 + t;
    int v = (i < SCAN_L) ? src[i] : 0;
    s[t] = v;
    __syncthreads();
    for (int o = 1; o < 512; o <<= 1) {
        int u = (t >= o) ? s[t - o] : 0;
        __syncthreads();
        s[t] += u;
        __syncthreads();
    }
    if (i < SCAN_L) dst[i] = bsum[blockIdx.x] + s[t] - v;  // exclusive prefix
}

// ---------------------------------------------------------------- pass 3: LDS-staged fill.
__global__ void __launch_bounds__(512, 4)
p3_fill_kernel(const int* __restrict__ ei,
               const int* __restrict__ mode_p,
               const int* __restrict__ bcnt,
               const int* __restrict__ boff,
               int* __restrict__ ebuf) {
    __shared__ int buf[CHUNK];          // 64 KB
    __shared__ int hist[BINS];
    __shared__ int lstart[BINS];
    __shared__ int cur[BINS];

    const int mode = *mode_p;
    int t = threadIdx.x;
    int blk = blockIdx.x;

    for (int j = t; j < BINS; j += 512) hist[j] = bcnt[j * BLK1 + blk];
    __syncthreads();

    // exclusive scan of hist[0..BINS) by wave 0: 13 bins/lane (64*13=832 >= 782)
    if (t < 64) {
        int base = t * 13;
        int run = 0;
        int loc[13];
#pragma unroll
        for (int u = 0; u < 13; ++u) {
            int idx = base + u;
            int v = (idx < BINS) ? hist[idx] : 0;
            loc[u] = run;
            run += v;
        }
        int inc = run;
        for (int o = 1; o < 64; o <<= 1) {
            int up = __shfl_up(inc, o);
            if (t >= o) inc += up;
        }
        int excl = inc - run;
#pragma unroll
        for (int u = 0; u < 13; ++u) {
            int idx = base + u;
            if (idx < BINS) { lstart[idx] = excl + loc[u]; cur[idx] = excl + loc[u]; }
        }
    }
    __syncthreads();

    // pass B: read edges, place into buf at sorted local position
    long long base = (long long)blk * CHUNK;
    int nthis = (int)(((long long)N_EDGES - base < (long long)CHUNK)
                      ? ((long long)N_EDGES - base) : (long long)CHUNK);
    for (int k = t; k < nthis; k += 512) {
        long long e = base + k;
        int d = load_idx(ei, (long long)N_EDGES + e, mode);
        if ((unsigned)d >= (unsigned)N_NODES) continue;
        int s = load_idx(ei, e, mode);
        s = min(max(s, 0), N_NODES - 1);         // memory-safety clamp (input always valid)
        int bin = d >> 8;
        int ld = d & 255;
        int pos = atomicAdd(&cur[bin], 1);       // local position in sorted order
        buf[pos] = s | (ld << 18);               // src:18 bits | local_dst:8 bits
    }
    __syncthreads();

    // write-out: wave w handles bins w, w+8, ... — contiguous coalesced bursts
    int wave = t >> 6, lane = t & 63;
    for (int bb = wave; bb < BINS; bb += 8) {
        int ls = lstart[bb];
        int ncnt = cur[bb] - ls;
        int gb = boff[bb * BLK1 + blk];
        for (int k = lane; k < ncnt; k += 64)
            ebuf[gb + k] = buf[ls + k];
    }
}

// ---------------------------------------------------------------- pass 5: per-bucket counting
// sort by COMPOSITE KEY (local_dst, src>>14); nodeoff/deg from bin scan; dis -> disf.
__global__ void p5_sort_kernel(int* __restrict__ ebuf,
                               const int* __restrict__ boff,
                               const int* __restrict__ total,
                               float* __restrict__ disf,
                               int* __restrict__ nodeoff,
                               int* __restrict__ flag) {
    __shared__ int buf[SORT_CAP];       // 35 KB
    __shared__ int bins[SBINS];         // 16 KB: counts -> absolute excl scan -> cursors
    __shared__ int part[512];

    int b = blockIdx.x;
    int t = threadIdx.x;
    for (int j = t; j < SBINS; j += 512) bins[j] = 0;
    __syncthreads();

    int start = boff[b * BLK1];
    int end = (b < BINS - 1) ? boff[(b + 1) * BLK1] : *total;
    int n = end - start;
    bool fit = (n <= SORT_CAP);

    for (int k = t; k < n; k += 512) {
        int v = __builtin_nontemporal_load(ebuf + start + k);
        int key = ((((unsigned)v) >> 18) << 4) | ((v & 0x3FFFF) >> 14);
        atomicAdd(&bins[key], 1);
        if (fit) buf[k] = v;
    }
    __syncthreads();

    // blocked exclusive scan of bins[0..SBINS) -> ABSOLUTE positions (+start)
    int base = t * 8;
    int loc[8];
    int run = 0;
#pragma unroll
    for (int u = 0; u < 8; ++u) { loc[u] = run; run += bins[base + u]; }
    part[t] = run;
    __syncthreads();
    for (int o = 1; o < 512; o <<= 1) {
        int u = (t >= o) ? part[t - o] : 0;
        __syncthreads();
        part[t] += u;
        __syncthreads();
    }
    int excl = part[t] - run;
#pragma unroll
    for (int u = 0; u < 8; ++u) bins[base + u] = start + excl + loc[u];
    __syncthreads();

    // nodeoff + dis (read bins BEFORE cursors get bumped)
    if (t < NPB) {
        int ns = bins[t * 16];
        nodeoff[b * NPB + t] = ns;
        int ne = (t < NPB - 1) ? bins[(t + 1) * 16] : end;
        int i = b * NPB + t;
        if (i < N_NODES) disf[i] = rsqrtf((float)((ne - ns) + 1));   // +1 self-loop
    }
    if (b == BINS - 1 && t == 0) nodeoff[BINS * NPB] = end;
    if (t == 0) flag[b] = fit ? 1 : 0;
    __syncthreads();

    if (!fit) return;
    // scatter back in (ld, src-window) order; bins[] cursors are ABSOLUTE
    for (int k = t; k < n; k += 512) {
        int v = buf[k];
        int key = ((((unsigned)v) >> 18) << 4) | ((v & 0x3FFFF) >> 14);
        int pos = atomicAdd(&bins[key], 1);
        ebuf[pos] = v;
    }
}

// ---------------------------------------------------------------- init2: h = (x @ W) * dis,
// packed fp16 into UNPADDED 20B rows (5 dwords) -> 4.0MB table, qb usually on qa's line.
__global__ void init2_kernel(const float* __restrict__ x,
                             const float* __restrict__ Wg,
                             const float* __restrict__ disf,
                             unsigned* __restrict__ htab) {
    __shared__ float Ws[F_IN * F_HID];
    for (int t = threadIdx.x; t < F_IN * F_HID; t += blockDim.x) Ws[t] = Wg[t];
    __syncthreads();

    int i = blockIdx.x * blockDim.x + threadIdx.x;
    if (i >= N_NODES) return;

    float acc[F_HID];
#pragma unroll
    for (int f = 0; f < F_HID; ++f) acc[f] = 0.0f;

    const float* xr = x + (long long)i * F_IN;
#pragma unroll
    for (int k = 0; k < F_IN; ++k) {
        float xv = xr[k];
#pragma unroll
        for (int f = 0; f < F_HID; ++f) acc[f] += xv * Ws[k * F_HID + f];
    }

    float di = disf[i];
    unsigned* rw = htab + (long long)i * 5;
#pragma unroll
    for (int k = 0; k < 5; ++k) {
        __half lo = __float2half(acc[2 * k] * di);
        __half hi = __float2half(acc[2 * k + 1] * di);
        rw[k] = ((unsigned)__half_as_ushort(hi) << 16) | (unsigned)__half_as_ushort(lo);
    }
}

// ---------------------------------------------------------------- pass 4b: per-node register
// gather-accumulate (NO atomics). 2 blocks/bucket, 128 nodes/block, 4 threads/node,
// batch-4, shfl_xor(1)+(2) combine. Gather = 20B row: 16B (align4) + 4B, ~1.3 lines/edge,
// 4.0MB table L2-resident. nt on streams.
__global__ void __launch_bounds__(512, 8)
p4b_acc_kernel(const int* __restrict__ ebuf,
               const int* __restrict__ nodeoff,
               const int* __restrict__ flag,
               const unsigned* __restrict__ htab,
               const float* __restrict__ disf,
               const float* __restrict__ b_gcn,
               const float* __restrict__ W_fc,
               const float* __restrict__ b_fc,
               float* __restrict__ out) {
    __shared__ float accs[128 * ACCP];   // fallback arm only
    __shared__ float Wfs[F_HID * F_OUT];
    __shared__ float bfs[F_OUT];
    __shared__ float bgs[F_HID];

    int bb = blockIdx.x >> 1;            // bucket
    int half = blockIdx.x & 1;           // which 128-node half
    int t = threadIdx.x;                 // 0..511
    int jl = t >> 2;                     // local node 0..127
    int par = t & 3;                     // parity within node quad
    if (t < F_HID * F_OUT) Wfs[t] = W_fc[t];
    if (t < F_OUT) bfs[t] = b_fc[t];
    if (t < F_HID) bgs[t] = b_gcn[t];
    __syncthreads();

    float* hidden = out;                               // [N, F_HID]
    floatx4* o24 = reinterpret_cast<floatx4*>(out + (long long)N_NODES * F_HID);

    int i = bb * NPB + half * 128 + jl;
    bool valid = (i < N_NODES);
    float acc[F_HID];
#pragma unroll
    for (int f = 0; f < F_HID; ++f) acc[f] = 0.0f;

    if (flag[bb]) {
        // ---------- fast arm: (ld, src-window)-sorted, register accumulation ----------
        int rs = valid ? nodeoff[i] : 0;
        int re = valid ? nodeoff[i + 1] : 0;
        for (int k0 = rs + par; k0 < re; k0 += 16) {   // this thread: k0, k0+4, k0+8, k0+12
            unsigned v[4]; uintx4 qa[4]; unsigned qb[4];
#pragma unroll
            for (int u = 0; u < 4; ++u)
                v[u] = (unsigned)__builtin_nontemporal_load(ebuf + min(k0 + 4 * u, re - 1));
#pragma unroll
            for (int u = 0; u < 4; ++u) {
                const unsigned* r = htab + (long long)(v[u] & 0x3FFFF) * 5;
                qa[u] = *reinterpret_cast<const uintx4_a4*>(r);
                qb[u] = r[4];
            }
#pragma unroll
            for (int u = 0; u < 4; ++u) {
                if (k0 + 4 * u < re) {
                    float2 f01 = up2(qa[u].x), f23 = up2(qa[u].y);
                    float2 f45 = up2(qa[u].z), f67 = up2(qa[u].w);
                    float2 f89 = up2(qb[u]);
                    acc[0] += f01.x; acc[1] += f01.y;
                    acc[2] += f23.x; acc[3] += f23.y;
                    acc[4] += f45.x; acc[5] += f45.y;
                    acc[6] += f67.x; acc[7] += f67.y;
                    acc[8] += f89.x; acc[9] += f89.y;
                }
            }
        }
    } else {
        // ---------- fallback arm: unsorted bucket, LDS atomics (never taken for valid input) ----
        for (int j = t; j < 128 * ACCP; j += blockDim.x) accs[j] = 0.0f;
        __syncthreads();
        int start = nodeoff[bb * NPB];
        int end = (bb < BINS - 1) ? nodeoff[(bb + 1) * NPB] : nodeoff[BINS * NPB];
        for (int e = start + t; e < end; e += blockDim.x) {
            unsigned v = (unsigned)ebuf[e];
            int s = v & 0x3FFFF;
            int ld = v >> 18;
            if ((ld >> 7) != half) continue;           // only this block's half
            const unsigned* r = htab + (long long)s * 5;
            uintx4 qa = *reinterpret_cast<const uintx4_a4*>(r);
            unsigned qb = r[4];
            float2 f01 = up2(qa.x), f23 = up2(qa.y), f45 = up2(qa.z), f67 = up2(qa.w), f89 = up2(qb);
            float* a = &accs[(ld - half * 128) * ACCP];
            atomicAdd(a + 0, f01.x); atomicAdd(a + 1, f01.y);
            atomicAdd(a + 2, f23.x); atomicAdd(a + 3, f23.y);
            atomicAdd(a + 4, f45.x); atomicAdd(a + 5, f45.y);
            atomicAdd(a + 6, f67.x); atomicAdd(a + 7, f67.y);
            atomicAdd(a + 8, f89.x); atomicAdd(a + 9, f89.y);
        }
        __syncthreads();
        if (par == 0) {                  // one lane per node takes the LDS sum; others stay 0
#pragma unroll
            for (int f = 0; f < F_HID; ++f) acc[f] = accs[jl * ACCP + f];
        }
    }

    // quad-combine: acc[node] = sum of 4 lanes
#pragma unroll
    for (int f = 0; f < F_HID; ++f) {
        acc[f] += __shfl_xor(acc[f], 1);
        acc[f] += __shfl_xor(acc[f], 2);
    }

    if (!valid || par) return;

    const unsigned* r = htab + (long long)i * 5;
    uintx4 qa = *reinterpret_cast<const uintx4_a4*>(r);
    unsigned qb = r[4];
    float di = disf[i];
    float2 f01 = up2(qa.x), f23 = up2(qa.y), f45 = up2(qa.z), f67 = up2(qa.w), f89 = up2(qb);
    float hp[F_HID] = {f01.x, f01.y, f23.x, f23.y, f45.x, f45.y, f67.x, f67.y, f89.x, f89.y};

    float hv[F_HID];
#pragma unroll
    for (int f = 0; f < F_HID; ++f) {
        hv[f] = (acc[f] + hp[f]) * di + bgs[f];    // (sum_nbrs h' + h'[i]) * dis[i] + b
        __builtin_nontemporal_store(hv[f], hidden + (long long)i * F_HID + f);
    }
    floatx4 o;
#pragma unroll
    for (int jj = 0; jj < F_OUT; ++jj) {
        float vv = bfs[jj];
#pragma unroll
        for (int f = 0; f < F_HID; ++f) vv += hv[f] * Wfs[f * F_OUT + jj];
        o[jj] = fmaxf(vv, 0.0f);
    }
    __builtin_nontemporal_store(o, o24 + i);
}

// ================================================================ FALLBACK (atomic scatter, small ws)
__global__ void fb_init_kernel(const float* __restrict__ x, const float* __restrict__ Wg,
                               float* __restrict__ hpad, float* __restrict__ deg,
                               float* __restrict__ hidden) {
    __shared__ float Ws[F_IN * F_HID];
    for (int t = threadIdx.x; t < F_IN * F_HID; t += blockDim.x) Ws[t] = Wg[t];
    __syncthreads();
    int i = blockIdx.x * blockDim.x + threadIdx.x;
    if (i >= N_NODES) return;
    float acc[F_HID];
#pragma unroll
    for (int f = 0; f < F_HID; ++f) acc[f] = 0.0f;
    const float* xr = x + (long long)i * F_IN;
#pragma unroll
    for (int k = 0; k < F_IN; ++k) {
        float xv = xr[k];
#pragma unroll
        for (int f = 0; f < F_HID; ++f) acc[f] += xv * Ws[k * F_HID + f];
    }
    float* hr = hpad + (long long)i * HPAD;
#pragma unroll
    for (int f = 0; f < F_HID; ++f) hr[f] = acc[f];
    hr[10] = 0.0f; hr[11] = 0.0f;
    deg[i] = 1.0f;
    float* hd = hidden + (long long)i * F_HID;
#pragma unroll
    for (int f = 0; f < F_HID; ++f) hd[f] = 0.0f;
}

__global__ void fb_deg_kernel(const int* __restrict__ ei, const int* __restrict__ mode_p,
                              float* __restrict__ deg) {
    const int mode = *mode_p;
    long long e = (long long)blockIdx.x * blockDim.x + threadIdx.x;
    if (e >= N_EDGES) return;
    int d = load_idx(ei, (long long)N_EDGES + e, mode);
    if ((unsigned)d < (unsigned)N_NODES) atomicAdd(&deg[d], 1.0f);
}

__global__ void fb_scatter_kernel(const int* __restrict__ ei, const int* __restrict__ mode_p,
                                  const float* __restrict__ hpad, const float* __restrict__ deg,
                                  float* __restrict__ hidden) {
    const int mode = *mode_p;
    long long e = (long long)blockIdx.x * blockDim.x + threadIdx.x;
    if (e >= N_EDGES) return;
    int s = load_idx(ei, e, mode);
    int d = load_idx(ei, (long long)N_EDGES + e, mode);
    if ((unsigned)s >= (unsigned)N_NODES || (unsigned)d >= (unsigned)N_NODES) return;
    float norm = rsqrtf(deg[s]) * rsqrtf(deg[d]);
    const float4* h4 = reinterpret_cast<const float4*>(hpad + (long long)s * HPAD);
    float4 a = h4[0]; float4 b = h4[1]; float4 c = h4[2];
    float* o = hidden + (long long)d * F_HID;
    atomicAdd(o + 0, a.x * norm); atomicAdd(o + 1, a.y * norm);
    atomicAdd(o + 2, a.z * norm); atomicAdd(o + 3, a.w * norm);
    atomicAdd(o + 4, b.x * norm); atomicAdd(o + 5, b.y * norm);
    atomicAdd(o + 6, b.z * norm); atomicAdd(o + 7, b.w * norm);
    atomicAdd(o + 8, c.x * norm); atomicAdd(o + 9, c.y * norm);
}

__global__ void fb_finalize_kernel(const float* __restrict__ hpad, const float* __restrict__ deg,
                                   const float* __restrict__ b_gcn, const float* __restrict__ W_fc,
                                   const float* __restrict__ b_fc, float* __restrict__ out) {
    __shared__ float Wf[F_HID * F_OUT];
    __shared__ float bf_s[F_OUT];
    __shared__ float bg_s[F_HID];
    for (int t = threadIdx.x; t < F_HID * F_OUT; t += blockDim.x) Wf[t] = W_fc[t];
    if (threadIdx.x < F_OUT) bf_s[threadIdx.x] = b_fc[threadIdx.x];
    if (threadIdx.x < F_HID) bg_s[threadIdx.x] = b_gcn[threadIdx.x];
    __syncthreads();
    int i = blockIdx.x * blockDim.x + threadIdx.x;
    if (i >= N_NODES) return;
    float* hidden = out;
    float* o2 = out + (long long)N_NODES * F_HID;
    float inv = 1.0f / deg[i];
    const float* hr = hpad + (long long)i * HPAD;
    float* hd = hidden + (long long)i * F_HID;
    float hv[F_HID];
#pragma unroll
    for (int f = 0; f < F_HID; ++f) {
        hv[f] = hd[f] + hr[f] * inv + bg_s[f];
        hd[f] = hv[f];
    }
#pragma unroll
    for (int j = 0; j < F_OUT; ++j) {
        float o = bf_s[j];
#pragma unroll
        for (int f = 0; f < F_HID; ++f) o += hv[f] * Wf[f * F_OUT + j];
        o2[(long long)i * F_OUT + j] = fmaxf(o, 0.0f);
    }
}

// ---------------------------------------------------------------- launch
extern "C" void kernel_launch(void* const* d_in, const int* in_sizes, int n_in,
                              void* d_out, int out_size, void* d_ws, size_t ws_size,
                              hipStream_t stream) {
    const float* x  = (const float*)d_in[0];
    const int*   ei = (const int*)d_in[1];
    const float* Wg = (const float*)d_in[2];
    const float* bg = (const float*)d_in[3];
    const float* Wf = (const float*)d_in[4];
    const float* bf = (const float*)d_in[5];
    float* out = (float*)d_out;

    const int nblk_node = (N_NODES + 255) / 256;     // 782

    // main ws layout (~34 MB)
    unsigned* htab    = (unsigned*)d_ws;                            // N*5 dwords = 4.0MB
    float*    disf    = (float*)(htab + (size_t)N_NODES * 5);       // N
    int*      bcnt    = (int*)(disf + N_NODES);                     // SCAN_L
    int*      boff    = bcnt + SCAN_L;                              // SCAN_L
    int*      bsum    = boff + SCAN_L;                              // 1024 (NA=598 used)
    int*      total   = bsum + 1024;                                // 1
    int*      nodeoff = total + 1;                                  // BINS*NPB+1
    int*      flag    = nodeoff + BINS * NPB + 1;                   // BINS
    int*      ebuf    = flag + BINS;                                // N_EDGES
    int*      mode    = ebuf + N_EDGES;                             // 1
    size_t need = (size_t)((char*)(mode + 1) - (char*)d_ws);

    if (ws_size >= need) {
        detect_mode_kernel<<<1, 64, 0, stream>>>(ei, mode);
        p1_count_kernel<<<BLK1, 512, 0, stream>>>(ei, mode, bcnt);
        scanA_kernel<<<NA, 512, 0, stream>>>(bcnt, bsum);
        scanB_kernel<<<1, 1024, 0, stream>>>(bsum, total);
        scanC_kernel<<<NA, 512, 0, stream>>>(bcnt, bsum, boff);
        p3_fill_kernel<<<BLK1, 512, 0, stream>>>(ei, mode, bcnt, boff, ebuf);
        p5_sort_kernel<<<BINS, 512, 0, stream>>>(ebuf, boff, total, disf, nodeoff, flag);
        init2_kernel<<<nblk_node, 256, 0, stream>>>(x, Wg, disf, htab);
        p4b_acc_kernel<<<BINS * 2, 512, 0, stream>>>(ebuf, nodeoff, flag, htab, disf,
                                                     bg, Wf, bf, out);
    } else {
        // fallback: atomic scatter (~10.4 MB)
        float* hpad  = (float*)d_ws;
        float* degf  = hpad + (size_t)N_NODES * HPAD;
        int*   mode2 = (int*)(degf + N_NODES);
        const int nblk_edge = (N_EDGES + 255) / 256;
        detect_mode_kernel<<<1, 64, 0, stream>>>(ei, mode2);
        fb_init_kernel<<<nblk_node, 256, 0, stream>>>(x, Wg, hpad, degf, out);
        fb_deg_kernel<<<nblk_edge, 256, 0, stream>>>(ei, mode2, degf);
        fb_scatter_kernel<<<nblk_edge, 256, 0, stream>>>(ei, mode2, hpad, degf, out);
        fb_finalize_kernel<<<nblk_node, 256, 0, stream>>>(hpad, degf, bg, Wf, bf, out);
    }
}

// Round 15
// 216.946 us; speedup vs baseline: 1.2259x; 1.1478x over previous
//
#include <hip/hip_runtime.h>
#include <hip/hip_fp16.h>

#define N_NODES 200000
#define N_EDGES 6400000
#define F_IN 34
#define F_HID 10
#define F_OUT 4
#define HPAD 12              // fb path only: 48B fp32 rows
#define BINS 782             // dst buckets
#define NPB 256              // nodes per bucket: 782*256 = 200192 >= N
#define CHUNK 16384
#define BLK1 ((N_EDGES + CHUNK - 1) / CHUNK)    // 391
#define SCAN_L (BINS * BLK1)                    // 305762
#define NA ((SCAN_L + 511) / 512)               // 598 (<= 1024 for scanB)
#define ACCP 11              // fallback-arm LDS acc padding
#define SORT_CAP 8960        // 35KB LDS in p5 -> 3 blocks/CU (8.6 sigma margin)
#define SBINS 4096           // p5 composite key: (ld<<4) | (src>>14)

typedef float floatx4 __attribute__((ext_vector_type(4)));     // nontemporal-store-compatible
typedef unsigned uintx4 __attribute__((ext_vector_type(4)));
typedef unsigned uintx4_a4 __attribute__((ext_vector_type(4), aligned(4)));  // 4B-aligned 16B load

// ---------------------------------------------------------------- helpers
__device__ __forceinline__ float2 up2(unsigned u) {
    __half2 h = *reinterpret_cast<const __half2*>(&u);
    return __half22float2(h);
}

// ---------------------------------------------------------------- mode detect
// int64 edge_index => every odd 32-bit word is zero (values < 2^31).
__global__ void detect_mode_kernel(const int* __restrict__ ei, int* __restrict__ mode) {
    int t = threadIdx.x;                 // 64 threads
    int v = ei[2 * t + 1];
    unsigned long long b = __ballot(v != 0);
    if (t == 0) *mode = (b == 0ull) ? 1 : 0;
}

__device__ __forceinline__ int load_idx(const int* ei, long long elem, int mode) {
    return mode ? ei[2 * elem] : ei[elem];
}

// ---------------------------------------------------------------- pass 1: bucket counts
// batch-4 MLP: 4 dst loads in flight before the LDS-atomic phase.
__global__ void p1_count_kernel(const int* __restrict__ ei,
                                const int* __restrict__ mode_p,
                                int* __restrict__ bcnt) {
    __shared__ int hist[BINS];
    const int mode = *mode_p;
    int t = threadIdx.x;
    for (int j = t; j < BINS; j += blockDim.x) hist[j] = 0;
    __syncthreads();

    long long base = (long long)blockIdx.x * CHUNK;
    int nthis = (int)(((long long)N_EDGES - base < (long long)CHUNK)
                      ? ((long long)N_EDGES - base) : (long long)CHUNK);
    for (int k0 = t; k0 < nthis; k0 += 2048) {
        int d[4];
#pragma unroll
        for (int u = 0; u < 4; ++u) {
            int k = k0 + u * 512;
            d[u] = (k < nthis) ? load_idx(ei, (long long)N_EDGES + base + k, mode) : -1;
        }
#pragma unroll
        for (int u = 0; u < 4; ++u)
            if ((unsigned)d[u] < (unsigned)N_NODES) atomicAdd(&hist[d[u] >> 8], 1);
    }
    __syncthreads();
    for (int j = t; j < BINS; j += blockDim.x)
        bcnt[j * BLK1 + blockIdx.x] = hist[j];   // bin-major
}

// ---------------------------------------------------------------- scan A: per-512-block sums
__global__ void scanA_kernel(const int* __restrict__ src, int* __restrict__ bsum) {
    __shared__ int s[512];
    int t = threadIdx.x;
    int i = blockIdx.x * 512 + t;
    s[t] = (i < SCAN_L) ? src[i] : 0;
    __syncthreads();
    for (int o = 256; o > 0; o >>= 1) {
        if (t < o) s[t] += s[t + o];
        __syncthreads();
    }
    if (t == 0) bsum[blockIdx.x] = s[0];
}

// ---------------------------------------------------------------- scan B: exclusive scan of NA block sums
__global__ void scanB_kernel(int* __restrict__ bsum, int* __restrict__ total) {
    __shared__ int s[1024];
    int t = threadIdx.x;
    int v = (t < NA) ? bsum[t] : 0;
    s[t] = v;
    __syncthreads();
    for (int o = 1; o < 1024; o <<= 1) {
        int u = (t >= o) ? s[t - o] : 0;
        __syncthreads();
        s[t] += u;
        __syncthreads();
    }
    if (t < NA) bsum[t] = s[t] - v;             // exclusive block offset
    if (t == 1023) *total = s[t];
}

// ---------------------------------------------------------------- scan C: produce boff (512-granule)
__global__ void scanC_kernel(const int* __restrict__ src,
                             const int* __restrict__ bsum,
                             int* __restrict__ dst) {
    __shared__ int s[512];
    int t = threadIdx.x;
    int i = blockIdx.x * 512 + t;
    int v = (i < SCAN_L) ? src[i] : 0;
    s[t] = v;
    __syncthreads();
    for (int o = 1; o < 512; o <<= 1) {
        int u = (t >= o) ? s[t - o] : 0;
        __syncthreads();
        s[t] += u;
        __syncthreads();
    }
    if (i < SCAN_L) dst[i] = bsum[blockIdx.x] + s[t] - v;  // exclusive prefix
}

// ---------------------------------------------------------------- pass 3: LDS-staged fill.
// batch-4 MLP in the placement pass: 8 global loads in flight per thread.
__global__ void __launch_bounds__(512, 2)
p3_fill_kernel(const int* __restrict__ ei,
               const int* __restrict__ mode_p,
               const int* __restrict__ bcnt,
               const int* __restrict__ boff,
               int* __restrict__ ebuf) {
    __shared__ int buf[CHUNK];          // 64 KB
    __shared__ int hist[BINS];
    __shared__ int lstart[BINS];
    __shared__ int cur[BINS];

    const int mode = *mode_p;
    int t = threadIdx.x;
    int blk = blockIdx.x;

    for (int j = t; j < BINS; j += 512) hist[j] = bcnt[j * BLK1 + blk];
    __syncthreads();

    // exclusive scan of hist[0..BINS) by wave 0: 13 bins/lane (64*13=832 >= 782)
    if (t < 64) {
        int base = t * 13;
        int run = 0;
        int loc[13];
#pragma unroll
        for (int u = 0; u < 13; ++u) {
            int idx = base + u;
            int v = (idx < BINS) ? hist[idx] : 0;
            loc[u] = run;
            run += v;
        }
        int inc = run;
        for (int o = 1; o < 64; o <<= 1) {
            int up = __shfl_up(inc, o);
            if (t >= o) inc += up;
        }
        int excl = inc - run;
#pragma unroll
        for (int u = 0; u < 13; ++u) {
            int idx = base + u;
            if (idx < BINS) { lstart[idx] = excl + loc[u]; cur[idx] = excl + loc[u]; }
        }
    }
    __syncthreads();

    // pass B: batch-4 read edges, place into buf at sorted local position
    long long base = (long long)blk * CHUNK;
    int nthis = (int)(((long long)N_EDGES - base < (long long)CHUNK)
                      ? ((long long)N_EDGES - base) : (long long)CHUNK);
    for (int k0 = t; k0 < nthis; k0 += 2048) {
        int d[4], s[4];
#pragma unroll
        for (int u = 0; u < 4; ++u) {
            int k = k0 + u * 512;
            if (k < nthis) {
                d[u] = load_idx(ei, (long long)N_EDGES + base + k, mode);
                s[u] = load_idx(ei, base + k, mode);
            } else d[u] = -1;
        }
#pragma unroll
        for (int u = 0; u < 4; ++u) {
            if ((unsigned)d[u] >= (unsigned)N_NODES) continue;
            int sv = min(max(s[u], 0), N_NODES - 1);   // memory-safety clamp
            int bin = d[u] >> 8;
            int ld = d[u] & 255;
            int pos = atomicAdd(&cur[bin], 1);         // local position in sorted order
            buf[pos] = sv | (ld << 18);                // src:18 bits | local_dst:8 bits
        }
    }
    __syncthreads();

    // write-out: wave w handles bins w, w+8, ... — contiguous coalesced bursts
    int wave = t >> 6, lane = t & 63;
    for (int bb = wave; bb < BINS; bb += 8) {
        int ls = lstart[bb];
        int ncnt = cur[bb] - ls;
        int gb = boff[bb * BLK1 + blk];
        for (int k = lane; k < ncnt; k += 64)
            ebuf[gb + k] = buf[ls + k];
    }
}

// ---------------------------------------------------------------- pass 5: per-bucket counting
// sort by COMPOSITE KEY (local_dst, src>>14); nodeoff/deg from bin scan; dis -> disf.
__global__ void p5_sort_kernel(int* __restrict__ ebuf,
                               const int* __restrict__ boff,
                               const int* __restrict__ total,
                               float* __restrict__ disf,
                               int* __restrict__ nodeoff,
                               int* __restrict__ flag) {
    __shared__ int buf[SORT_CAP];       // 35 KB
    __shared__ int bins[SBINS];         // 16 KB: counts -> absolute excl scan -> cursors
    __shared__ int part[512];

    int b = blockIdx.x;
    int t = threadIdx.x;
    for (int j = t; j < SBINS; j += 512) bins[j] = 0;
    __syncthreads();

    int start = boff[b * BLK1];
    int end = (b < BINS - 1) ? boff[(b + 1) * BLK1] : *total;
    int n = end - start;
    bool fit = (n <= SORT_CAP);

    for (int k = t; k < n; k += 512) {
        int v = __builtin_nontemporal_load(ebuf + start + k);
        int key = ((((unsigned)v) >> 18) << 4) | ((v & 0x3FFFF) >> 14);
        atomicAdd(&bins[key], 1);
        if (fit) buf[k] = v;
    }
    __syncthreads();

    // blocked exclusive scan of bins[0..SBINS) -> ABSOLUTE positions (+start)
    int base = t * 8;
    int loc[8];
    int run = 0;
#pragma unroll
    for (int u = 0; u < 8; ++u) { loc[u] = run; run += bins[base + u]; }
    part[t] = run;
    __syncthreads();
    for (int o = 1; o < 512; o <<= 1) {
        int u = (t >= o) ? part[t - o] : 0;
        __syncthreads();
        part[t] += u;
        __syncthreads();
    }
    int excl = part[t] - run;
#pragma unroll
    for (int u = 0; u < 8; ++u) bins[base + u] = start + excl + loc[u];
    __syncthreads();

    // nodeoff + dis (read bins BEFORE cursors get bumped)
    if (t < NPB) {
        int ns = bins[t * 16];
        nodeoff[b * NPB + t] = ns;
        int ne = (t < NPB - 1) ? bins[(t + 1) * 16] : end;
        int i = b * NPB + t;
        if (i < N_NODES) disf[i] = rsqrtf((float)((ne - ns) + 1));   // +1 self-loop
    }
    if (b == BINS - 1 && t == 0) nodeoff[BINS * NPB] = end;
    if (t == 0) flag[b] = fit ? 1 : 0;
    __syncthreads();

    if (!fit) return;
    // scatter back in (ld, src-window) order; bins[] cursors are ABSOLUTE
    for (int k = t; k < n; k += 512) {
        int v = buf[k];
        int key = ((((unsigned)v) >> 18) << 4) | ((v & 0x3FFFF) >> 14);
        int pos = atomicAdd(&bins[key], 1);
        ebuf[pos] = v;
    }
}

// ---------------------------------------------------------------- init2: h = (x @ W) * dis,
// packed fp16 into UNPADDED 20B rows (5 dwords) -> 4.0MB table, qb usually on qa's line.
__global__ void init2_kernel(const float* __restrict__ x,
                             const float* __restrict__ Wg,
                             const float* __restrict__ disf,
                             unsigned* __restrict__ htab) {
    __shared__ float Ws[F_IN * F_HID];
    for (int t = threadIdx.x; t < F_IN * F_HID; t += blockDim.x) Ws[t] = Wg[t];
    __syncthreads();

    int i = blockIdx.x * blockDim.x + threadIdx.x;
    if (i >= N_NODES) return;

    float acc[F_HID];
#pragma unroll
    for (int f = 0; f < F_HID; ++f) acc[f] = 0.0f;

    const float* xr = x + (long long)i * F_IN;
#pragma unroll
    for (int k = 0; k < F_IN; ++k) {
        float xv = xr[k];
#pragma unroll
        for (int f = 0; f < F_HID; ++f) acc[f] += xv * Ws[k * F_HID + f];
    }

    float di = disf[i];
    unsigned* rw = htab + (long long)i * 5;
#pragma unroll
    for (int k = 0; k < 5; ++k) {
        __half lo = __float2half(acc[2 * k] * di);
        __half hi = __float2half(acc[2 * k + 1] * di);
        rw[k] = ((unsigned)__half_as_ushort(hi) << 16) | (unsigned)__half_as_ushort(lo);
    }
}

// ---------------------------------------------------------------- pass 4b: per-node register
// gather-accumulate (NO atomics). 4 blocks/bucket, 64 nodes/block, 8 threads/node,
// batch-4 => 32 loads in flight per node (covers deg~32 in ONE round),
// shfl_xor(1)+(2)+(4) combine. 20B rows, 4.0MB L2-resident table. nt on streams.
__global__ void __launch_bounds__(512, 8)
p4b_acc_kernel(const int* __restrict__ ebuf,
               const int* __restrict__ nodeoff,
               const int* __restrict__ flag,
               const unsigned* __restrict__ htab,
               const float* __restrict__ disf,
               const float* __restrict__ b_gcn,
               const float* __restrict__ W_fc,
               const float* __restrict__ b_fc,
               float* __restrict__ out) {
    __shared__ float accs[64 * ACCP];    // fallback arm only
    __shared__ float Wfs[F_HID * F_OUT];
    __shared__ float bfs[F_OUT];
    __shared__ float bgs[F_HID];

    int bb = blockIdx.x >> 2;            // bucket
    int q  = blockIdx.x & 3;             // which 64-node quarter
    int t = threadIdx.x;                 // 0..511
    int jl = t >> 3;                     // local node 0..63
    int par = t & 7;                     // lane within node octet
    if (t < F_HID * F_OUT) Wfs[t] = W_fc[t];
    if (t < F_OUT) bfs[t] = b_fc[t];
    if (t < F_HID) bgs[t] = b_gcn[t];
    __syncthreads();

    float* hidden = out;                               // [N, F_HID]
    floatx4* o24 = reinterpret_cast<floatx4*>(out + (long long)N_NODES * F_HID);

    int i = bb * NPB + q * 64 + jl;
    bool valid = (i < N_NODES);
    float acc[F_HID];
#pragma unroll
    for (int f = 0; f < F_HID; ++f) acc[f] = 0.0f;

    if (flag[bb]) {
        // ---------- fast arm: (ld, src-window)-sorted, register accumulation ----------
        int rs = valid ? nodeoff[i] : 0;
        int re = valid ? nodeoff[i + 1] : 0;
        for (int k0 = rs + par; k0 < re; k0 += 32) {   // this thread: k0, k0+8, k0+16, k0+24
            unsigned v[4]; uintx4 qa[4]; unsigned qb[4];
#pragma unroll
            for (int u = 0; u < 4; ++u)
                v[u] = (unsigned)__builtin_nontemporal_load(ebuf + min(k0 + 8 * u, re - 1));
#pragma unroll
            for (int u = 0; u < 4; ++u) {
                const unsigned* r = htab + (long long)(v[u] & 0x3FFFF) * 5;
                qa[u] = *reinterpret_cast<const uintx4_a4*>(r);
                qb[u] = r[4];
            }
#pragma unroll
            for (int u = 0; u < 4; ++u) {
                if (k0 + 8 * u < re) {
                    float2 f01 = up2(qa[u].x), f23 = up2(qa[u].y);
                    float2 f45 = up2(qa[u].z), f67 = up2(qa[u].w);
                    float2 f89 = up2(qb[u]);
                    acc[0] += f01.x; acc[1] += f01.y;
                    acc[2] += f23.x; acc[3] += f23.y;
                    acc[4] += f45.x; acc[5] += f45.y;
                    acc[6] += f67.x; acc[7] += f67.y;
                    acc[8] += f89.x; acc[9] += f89.y;
                }
            }
        }
    } else {
        // ---------- fallback arm: unsorted bucket, LDS atomics (never taken for valid input) ----
        for (int j = t; j < 64 * ACCP; j += blockDim.x) accs[j] = 0.0f;
        __syncthreads();
        int start = nodeoff[bb * NPB];
        int end = (bb < BINS - 1) ? nodeoff[(bb + 1) * NPB] : nodeoff[BINS * NPB];
        for (int e = start + t; e < end; e += blockDim.x) {
            unsigned v = (unsigned)ebuf[e];
            int s = v & 0x3FFFF;
            int ld = v >> 18;
            if ((ld >> 6) != q) continue;              // only this block's quarter
            const unsigned* r = htab + (long long)s * 5;
            uintx4 qa = *reinterpret_cast<const uintx4_a4*>(r);
            unsigned qb = r[4];
            float2 f01 = up2(qa.x), f23 = up2(qa.y), f45 = up2(qa.z), f67 = up2(qa.w), f89 = up2(qb);
            float* a = &accs[(ld - q * 64) * ACCP];
            atomicAdd(a + 0, f01.x); atomicAdd(a + 1, f01.y);
            atomicAdd(a + 2, f23.x); atomicAdd(a + 3, f23.y);
            atomicAdd(a + 4, f45.x); atomicAdd(a + 5, f45.y);
            atomicAdd(a + 6, f67.x); atomicAdd(a + 7, f67.y);
            atomicAdd(a + 8, f89.x); atomicAdd(a + 9, f89.y);
        }
        __syncthreads();
        if (par == 0) {                  // one lane per node takes the LDS sum; others stay 0
#pragma unroll
            for (int f = 0; f < F_HID; ++f) acc[f] = accs[jl * ACCP + f];
        }
    }

    // octet-combine: acc[node] = sum of 8 lanes
#pragma unroll
    for (int f = 0; f < F_HID; ++f) {
        acc[f] += __shfl_xor(acc[f], 1);
        acc[f] += __shfl_xor(acc[f], 2);
        acc[f] += __shfl_xor(acc[f], 4);
    }

    if (!valid || par) return;

    const unsigned* r = htab + (long long)i * 5;
    uintx4 qa = *reinterpret_cast<const uintx4_a4*>(r);
    unsigned qb = r[4];
    float di = disf[i];
    float2 f01 = up2(qa.x), f23 = up2(qa.y), f45 = up2(qa.z), f67 = up2(qa.w), f89 = up2(qb);
    float hp[F_HID] = {f01.x, f01.y, f23.x, f23.y, f45.x, f45.y, f67.x, f67.y, f89.x, f89.y};

    float hv[F_HID];
#pragma unroll
    for (int f = 0; f < F_HID; ++f) {
        hv[f] = (acc[f] + hp[f]) * di + bgs[f];    // (sum_nbrs h' + h'[i]) * dis[i] + b
        __builtin_nontemporal_store(hv[f], hidden + (long long)i * F_HID + f);
    }
    floatx4 o;
#pragma unroll
    for (int jj = 0; jj < F_OUT; ++jj) {
        float vv = bfs[jj];
#pragma unroll
        for (int f = 0; f < F_HID; ++f) vv += hv[f] * Wfs[f * F_OUT + jj];
        o[jj] = fmaxf(vv, 0.0f);
    }
    __builtin_nontemporal_store(o, o24 + i);
}

// ================================================================ FALLBACK (atomic scatter, small ws)
__global__ void fb_init_kernel(const float* __restrict__ x, const float* __restrict__ Wg,
                               float* __restrict__ hpad, float* __restrict__ deg,
                               float* __restrict__ hidden) {
    __shared__ float Ws[F_IN * F_HID];
    for (int t = threadIdx.x; t < F_IN * F_HID; t += blockDim.x) Ws[t] = Wg[t];
    __syncthreads();
    int i = blockIdx.x * blockDim.x + threadIdx.x;
    if (i >= N_NODES) return;
    float acc[F_HID];
#pragma unroll
    for (int f = 0; f < F_HID; ++f) acc[f] = 0.0f;
    const float* xr = x + (long long)i * F_IN;
#pragma unroll
    for (int k = 0; k < F_IN; ++k) {
        float xv = xr[k];
#pragma unroll
        for (int f = 0; f < F_HID; ++f) acc[f] += xv * Ws[k * F_HID + f];
    }
    float* hr = hpad + (long long)i * HPAD;
#pragma unroll
    for (int f = 0; f < F_HID; ++f) hr[f] = acc[f];
    hr[10] = 0.0f; hr[11] = 0.0f;
    deg[i] = 1.0f;
    float* hd = hidden + (long long)i * F_HID;
#pragma unroll
    for (int f = 0; f < F_HID; ++f) hd[f] = 0.0f;
}

__global__ void fb_deg_kernel(const int* __restrict__ ei, const int* __restrict__ mode_p,
                              float* __restrict__ deg) {
    const int mode = *mode_p;
    long long e = (long long)blockIdx.x * blockDim.x + threadIdx.x;
    if (e >= N_EDGES) return;
    int d = load_idx(ei, (long long)N_EDGES + e, mode);
    if ((unsigned)d < (unsigned)N_NODES) atomicAdd(&deg[d], 1.0f);
}

__global__ void fb_scatter_kernel(const int* __restrict__ ei, const int* __restrict__ mode_p,
                                  const float* __restrict__ hpad, const float* __restrict__ deg,
                                  float* __restrict__ hidden) {
    const int mode = *mode_p;
    long long e = (long long)blockIdx.x * blockDim.x + threadIdx.x;
    if (e >= N_EDGES) return;
    int s = load_idx(ei, e, mode);
    int d = load_idx(ei, (long long)N_EDGES + e, mode);
    if ((unsigned)s >= (unsigned)N_NODES || (unsigned)d >= (unsigned)N_NODES) return;
    float norm = rsqrtf(deg[s]) * rsqrtf(deg[d]);
    const float4* h4 = reinterpret_cast<const float4*>(hpad + (long long)s * HPAD);
    float4 a = h4[0]; float4 b = h4[1]; float4 c = h4[2];
    float* o = hidden + (long long)d * F_HID;
    atomicAdd(o + 0, a.x * norm); atomicAdd(o + 1, a.y * norm);
    atomicAdd(o + 2, a.z * norm); atomicAdd(o + 3, a.w * norm);
    atomicAdd(o + 4, b.x * norm); atomicAdd(o + 5, b.y * norm);
    atomicAdd(o + 6, b.z * norm); atomicAdd(o + 7, b.w * norm);
    atomicAdd(o + 8, c.x * norm); atomicAdd(o + 9, c.y * norm);
}

__global__ void fb_finalize_kernel(const float* __restrict__ hpad, const float* __restrict__ deg,
                                   const float* __restrict__ b_gcn, const float* __restrict__ W_fc,
                                   const float* __restrict__ b_fc, float* __restrict__ out) {
    __shared__ float Wf[F_HID * F_OUT];
    __shared__ float bf_s[F_OUT];
    __shared__ float bg_s[F_HID];
    for (int t = threadIdx.x; t < F_HID * F_OUT; t += blockDim.x) Wf[t] = W_fc[t];
    if (threadIdx.x < F_OUT) bf_s[threadIdx.x] = b_fc[threadIdx.x];
    if (threadIdx.x < F_HID) bg_s[threadIdx.x] = b_gcn[threadIdx.x];
    __syncthreads();
    int i = blockIdx.x * blockDim.x + threadIdx.x;
    if (i >= N_NODES) return;
    float* hidden = out;
    float* o2 = out + (long long)N_NODES * F_HID;
    float inv = 1.0f / deg[i];
    const float* hr = hpad + (long long)i * HPAD;
    float* hd = hidden + (long long)i * F_HID;
    float hv[F_HID];
#pragma unroll
    for (int f = 0; f < F_HID; ++f) {
        hv[f] = hd[f] + hr[f] * inv + bg_s[f];
        hd[f] = hv[f];
    }
#pragma unroll
    for (int j = 0; j < F_OUT; ++j) {
        float o = bf_s[j];
#pragma unroll
        for (int f = 0; f < F_HID; ++f) o += hv[f] * Wf[f * F_OUT + j];
        o2[(long long)i * F_OUT + j] = fmaxf(o, 0.0f);
    }
}

// ---------------------------------------------------------------- launch
extern "C" void kernel_launch(void* const* d_in, const int* in_sizes, int n_in,
                              void* d_out, int out_size, void* d_ws, size_t ws_size,
                              hipStream_t stream) {
    const float* x  = (const float*)d_in[0];
    const int*   ei = (const int*)d_in[1];
    const float* Wg = (const float*)d_in[2];
    const float* bg = (const float*)d_in[3];
    const float* Wf = (const float*)d_in[4];
    const float* bf = (const float*)d_in[5];
    float* out = (float*)d_out;

    const int nblk_node = (N_NODES + 255) / 256;     // 782

    // main ws layout (~34 MB)
    unsigned* htab    = (unsigned*)d_ws;                            // N*5 dwords = 4.0MB
    float*    disf    = (float*)(htab + (size_t)N_NODES * 5);       // N
    int*      bcnt    = (int*)(disf + N_NODES);                     // SCAN_L
    int*      boff    = bcnt + SCAN_L;                              // SCAN_L
    int*      bsum    = boff + SCAN_L;                              // 1024 (NA=598 used)
    int*      total   = bsum + 1024;                                // 1
    int*      nodeoff = total + 1;                                  // BINS*NPB+1
    int*      flag    = nodeoff + BINS * NPB + 1;                   // BINS
    int*      ebuf    = flag + BINS;                                // N_EDGES
    int*      mode    = ebuf + N_EDGES;                             // 1
    size_t need = (size_t)((char*)(mode + 1) - (char*)d_ws);

    if (ws_size >= need) {
        detect_mode_kernel<<<1, 64, 0, stream>>>(ei, mode);
        p1_count_kernel<<<BLK1, 512, 0, stream>>>(ei, mode, bcnt);
        scanA_kernel<<<NA, 512, 0, stream>>>(bcnt, bsum);
        scanB_kernel<<<1, 1024, 0, stream>>>(bsum, total);
        scanC_kernel<<<NA, 512, 0, stream>>>(bcnt, bsum, boff);
        p3_fill_kernel<<<BLK1, 512, 0, stream>>>(ei, mode, bcnt, boff, ebuf);
        p5_sort_kernel<<<BINS, 512, 0, stream>>>(ebuf, boff, total, disf, nodeoff, flag);
        init2_kernel<<<nblk_node, 256, 0, stream>>>(x, Wg, disf, htab);
        p4b_acc_kernel<<<BINS * 4, 512, 0, stream>>>(ebuf, nodeoff, flag, htab, disf,
                                                     bg, Wf, bf, out);
    } else {
        // fallback: atomic scatter (~10.4 MB)
        float* hpad  = (float*)d_ws;
        float* degf  = hpad + (size_t)N_NODES * HPAD;
        int*   mode2 = (int*)(degf + N_NODES);
        const int nblk_edge = (N_EDGES + 255) / 256;
        detect_mode_kernel<<<1, 64, 0, stream>>>(ei, mode2);
        fb_init_kernel<<<nblk_node, 256, 0, stream>>>(x, Wg, hpad, degf, out);
        fb_deg_kernel<<<nblk_edge, 256, 0, stream>>>(ei, mode2, degf);
        fb_scatter_kernel<<<nblk_edge, 256, 0, stream>>>(ei, mode2, hpad, degf, out);
        fb_finalize_kernel<<<nblk_node, 256, 0, stream>>>(hpad, degf, bg, Wf, bf, out);
    }
}

// Round 16
// 190.888 us; speedup vs baseline: 1.3932x; 1.1365x over previous
//
#include <hip/hip_runtime.h>
#include <hip/hip_fp16.h>

#define N_NODES 200000
#define N_EDGES 6400000
#define F_IN 34
#define F_HID 10
#define F_OUT 4
#define HPAD 12              // fb path only: 48B fp32 rows
#define BINS 782             // dst buckets
#define NPB 256              // nodes per bucket: 782*256 = 200192 >= N
#define CHUNK 16384
#define BLK1 ((N_EDGES + CHUNK - 1) / CHUNK)    // 391
#define SCAN_L (BINS * BLK1)                    // 305762
#define NA ((SCAN_L + 511) / 512)               // 598 (<= 1024 for scanB)
#define ACCP 11              // fallback-arm LDS acc padding
#define SORT_CAP 8960        // 35KB LDS in p5 (8.6 sigma margin over 8184 mean)
#define SBINS 4096           // p5 composite key: (ld<<4) | (src>>14)

typedef float floatx4 __attribute__((ext_vector_type(4)));     // nontemporal-store-compatible
typedef unsigned uintx4 __attribute__((ext_vector_type(4)));
typedef unsigned uintx4_a4 __attribute__((ext_vector_type(4), aligned(4)));  // 4B-aligned 16B load

// ---------------------------------------------------------------- helpers
__device__ __forceinline__ float2 up2(unsigned u) {
    __half2 h = *reinterpret_cast<const __half2*>(&u);
    return __half22float2(h);
}

// ---------------------------------------------------------------- mode detect
// int64 edge_index => every odd 32-bit word is zero (values < 2^31).
__global__ void detect_mode_kernel(const int* __restrict__ ei, int* __restrict__ mode) {
    int t = threadIdx.x;                 // 64 threads
    int v = ei[2 * t + 1];
    unsigned long long b = __ballot(v != 0);
    if (t == 0) *mode = (b == 0ull) ? 1 : 0;
}

__device__ __forceinline__ int load_idx(const int* ei, long long elem, int mode) {
    return mode ? ei[2 * elem] : ei[elem];
}

// ---------------------------------------------------------------- pass 1: bucket counts
// 1024 threads, batch-4 MLP.
__global__ void __launch_bounds__(1024, 8)
p1_count_kernel(const int* __restrict__ ei,
                const int* __restrict__ mode_p,
                int* __restrict__ bcnt) {
    __shared__ int hist[BINS];
    const int mode = *mode_p;
    int t = threadIdx.x;
    for (int j = t; j < BINS; j += 1024) hist[j] = 0;
    __syncthreads();

    long long base = (long long)blockIdx.x * CHUNK;
    int nthis = (int)(((long long)N_EDGES - base < (long long)CHUNK)
                      ? ((long long)N_EDGES - base) : (long long)CHUNK);
    for (int k0 = t; k0 < nthis; k0 += 4096) {
        int d[4];
#pragma unroll
        for (int u = 0; u < 4; ++u) {
            int k = k0 + u * 1024;
            d[u] = (k < nthis) ? load_idx(ei, (long long)N_EDGES + base + k, mode) : -1;
        }
#pragma unroll
        for (int u = 0; u < 4; ++u)
            if ((unsigned)d[u] < (unsigned)N_NODES) atomicAdd(&hist[d[u] >> 8], 1);
    }
    __syncthreads();
    for (int j = t; j < BINS; j += 1024)
        bcnt[j * BLK1 + blockIdx.x] = hist[j];   // bin-major
}

// ---------------------------------------------------------------- scan A: per-512-block sums
__global__ void scanA_kernel(const int* __restrict__ src, int* __restrict__ bsum) {
    __shared__ int s[512];
    int t = threadIdx.x;
    int i = blockIdx.x * 512 + t;
    s[t] = (i < SCAN_L) ? src[i] : 0;
    __syncthreads();
    for (int o = 256; o > 0; o >>= 1) {
        if (t < o) s[t] += s[t + o];
        __syncthreads();
    }
    if (t == 0) bsum[blockIdx.x] = s[0];
}

// ---------------------------------------------------------------- scan B: exclusive scan of NA block sums
__global__ void scanB_kernel(int* __restrict__ bsum, int* __restrict__ total) {
    __shared__ int s[1024];
    int t = threadIdx.x;
    int v = (t < NA) ? bsum[t] : 0;
    s[t] = v;
    __syncthreads();
    for (int o = 1; o < 1024; o <<= 1) {
        int u = (t >= o) ? s[t - o] : 0;
        __syncthreads();
        s[t] += u;
        __syncthreads();
    }
    if (t < NA) bsum[t] = s[t] - v;             // exclusive block offset
    if (t == 1023) *total = s[t];
}

// ---------------------------------------------------------------- scan C: produce boff (512-granule)
__global__ void scanC_kernel(const int* __restrict__ src,
                             const int* __restrict__ bsum,
                             int* __restrict__ dst) {
    __shared__ int s[512];
    int t = threadIdx.x;
    int i = blockIdx.x * 512 + t;
    int v = (i < SCAN_L) ? src[i] : 0;
    s[t] = v;
    __syncthreads();
    for (int o = 1; o < 512; o <<= 1) {
        int u = (t >= o) ? s[t - o] : 0;
        __syncthreads();
        s[t] += u;
        __syncthreads();
    }
    if (i < SCAN_L) dst[i] = bsum[blockIdx.x] + s[t] - v;  // exclusive prefix
}

// ---------------------------------------------------------------- pass 3: LDS-staged fill.
// 1024 threads (32 waves/CU at 2 blocks), batch-4 MLP placement, coalesced burst write-out.
__global__ void __launch_bounds__(1024, 8)
p3_fill_kernel(const int* __restrict__ ei,
               const int* __restrict__ mode_p,
               const int* __restrict__ bcnt,
               const int* __restrict__ boff,
               int* __restrict__ ebuf) {
    __shared__ int buf[CHUNK];          // 64 KB
    __shared__ int hist[BINS];
    __shared__ int lstart[BINS];
    __shared__ int cur[BINS];

    const int mode = *mode_p;
    int t = threadIdx.x;
    int blk = blockIdx.x;

    for (int j = t; j < BINS; j += 1024) hist[j] = bcnt[j * BLK1 + blk];
    __syncthreads();

    // exclusive scan of hist[0..BINS) by wave 0: 13 bins/lane (64*13=832 >= 782)
    if (t < 64) {
        int base = t * 13;
        int run = 0;
        int loc[13];
#pragma unroll
        for (int u = 0; u < 13; ++u) {
            int idx = base + u;
            int v = (idx < BINS) ? hist[idx] : 0;
            loc[u] = run;
            run += v;
        }
        int inc = run;
        for (int o = 1; o < 64; o <<= 1) {
            int up = __shfl_up(inc, o);
            if (t >= o) inc += up;
        }
        int excl = inc - run;
#pragma unroll
        for (int u = 0; u < 13; ++u) {
            int idx = base + u;
            if (idx < BINS) { lstart[idx] = excl + loc[u]; cur[idx] = excl + loc[u]; }
        }
    }
    __syncthreads();

    // pass B: batch-4 read edges, place into buf at sorted local position
    long long base = (long long)blk * CHUNK;
    int nthis = (int)(((long long)N_EDGES - base < (long long)CHUNK)
                      ? ((long long)N_EDGES - base) : (long long)CHUNK);
    for (int k0 = t; k0 < nthis; k0 += 4096) {
        int d[4], s[4];
#pragma unroll
        for (int u = 0; u < 4; ++u) {
            int k = k0 + u * 1024;
            if (k < nthis) {
                d[u] = load_idx(ei, (long long)N_EDGES + base + k, mode);
                s[u] = load_idx(ei, base + k, mode);
            } else d[u] = -1;
        }
#pragma unroll
        for (int u = 0; u < 4; ++u) {
            if ((unsigned)d[u] >= (unsigned)N_NODES) continue;
            int sv = min(max(s[u], 0), N_NODES - 1);   // memory-safety clamp
            int bin = d[u] >> 8;
            int ld = d[u] & 255;
            int pos = atomicAdd(&cur[bin], 1);         // local position in sorted order
            buf[pos] = sv | (ld << 18);                // src:18 bits | local_dst:8 bits
        }
    }
    __syncthreads();

    // write-out: wave w (of 16) handles bins w, w+16, ... — contiguous coalesced bursts
    int wave = t >> 6, lane = t & 63;
    for (int bb = wave; bb < BINS; bb += 16) {
        int ls = lstart[bb];
        int ncnt = cur[bb] - ls;
        int gb = boff[bb * BLK1 + blk];
        for (int k = lane; k < ncnt; k += 64)
            ebuf[gb + k] = buf[ls + k];
    }
}

// ---------------------------------------------------------------- pass 5: per-bucket counting
// sort by COMPOSITE KEY (local_dst, src>>14). 1024 threads (32 waves/CU at 2 blocks).
__global__ void __launch_bounds__(1024, 8)
p5_sort_kernel(int* __restrict__ ebuf,
               const int* __restrict__ boff,
               const int* __restrict__ total,
               float* __restrict__ disf,
               int* __restrict__ nodeoff,
               int* __restrict__ flag) {
    __shared__ int buf[SORT_CAP];       // 35 KB
    __shared__ int bins[SBINS];         // 16 KB: counts -> absolute excl scan -> cursors
    __shared__ int part[1024];          // 4 KB

    int b = blockIdx.x;
    int t = threadIdx.x;
    for (int j = t; j < SBINS; j += 1024) bins[j] = 0;
    __syncthreads();

    int start = boff[b * BLK1];
    int end = (b < BINS - 1) ? boff[(b + 1) * BLK1] : *total;
    int n = end - start;
    bool fit = (n <= SORT_CAP);

    for (int k = t; k < n; k += 1024) {
        int v = __builtin_nontemporal_load(ebuf + start + k);
        int key = ((((unsigned)v) >> 18) << 4) | ((v & 0x3FFFF) >> 14);
        atomicAdd(&bins[key], 1);
        if (fit) buf[k] = v;
    }
    __syncthreads();

    // blocked exclusive scan of bins[0..SBINS): 4 bins/thread -> ABSOLUTE positions (+start)
    int base = t * 4;
    int loc[4];
    int run = 0;
#pragma unroll
    for (int u = 0; u < 4; ++u) { loc[u] = run; run += bins[base + u]; }
    part[t] = run;
    __syncthreads();
    for (int o = 1; o < 1024; o <<= 1) {
        int u = (t >= o) ? part[t - o] : 0;
        __syncthreads();
        part[t] += u;
        __syncthreads();
    }
    int excl = part[t] - run;
#pragma unroll
    for (int u = 0; u < 4; ++u) bins[base + u] = start + excl + loc[u];
    __syncthreads();

    // nodeoff + dis (read bins BEFORE cursors get bumped)
    if (t < NPB) {
        int ns = bins[t * 16];
        nodeoff[b * NPB + t] = ns;
        int ne = (t < NPB - 1) ? bins[(t + 1) * 16] : end;
        int i = b * NPB + t;
        if (i < N_NODES) disf[i] = rsqrtf((float)((ne - ns) + 1));   // +1 self-loop
    }
    if (b == BINS - 1 && t == 0) nodeoff[BINS * NPB] = end;
    if (t == 0) flag[b] = fit ? 1 : 0;
    __syncthreads();

    if (!fit) return;
    // scatter back in (ld, src-window) order; bins[] cursors are ABSOLUTE
    for (int k = t; k < n; k += 1024) {
        int v = buf[k];
        int key = ((((unsigned)v) >> 18) << 4) | ((v & 0x3FFFF) >> 14);
        int pos = atomicAdd(&bins[key], 1);
        ebuf[pos] = v;
    }
}

// ---------------------------------------------------------------- init2: h = (x @ W) * dis,
// packed fp16 into UNPADDED 20B rows (5 dwords) -> 4.0MB table, qb usually on qa's line.
__global__ void init2_kernel(const float* __restrict__ x,
                             const float* __restrict__ Wg,
                             const float* __restrict__ disf,
                             unsigned* __restrict__ htab) {
    __shared__ float Ws[F_IN * F_HID];
    for (int t = threadIdx.x; t < F_IN * F_HID; t += blockDim.x) Ws[t] = Wg[t];
    __syncthreads();

    int i = blockIdx.x * blockDim.x + threadIdx.x;
    if (i >= N_NODES) return;

    float acc[F_HID];
#pragma unroll
    for (int f = 0; f < F_HID; ++f) acc[f] = 0.0f;

    const float* xr = x + (long long)i * F_IN;
#pragma unroll
    for (int k = 0; k < F_IN; ++k) {
        float xv = xr[k];
#pragma unroll
        for (int f = 0; f < F_HID; ++f) acc[f] += xv * Ws[k * F_HID + f];
    }

    float di = disf[i];
    unsigned* rw = htab + (long long)i * 5;
#pragma unroll
    for (int k = 0; k < 5; ++k) {
        __half lo = __float2half(acc[2 * k] * di);
        __half hi = __float2half(acc[2 * k + 1] * di);
        rw[k] = ((unsigned)__half_as_ushort(hi) << 16) | (unsigned)__half_as_ushort(lo);
    }
}

// ---------------------------------------------------------------- pass 4b: per-node register
// gather-accumulate (NO atomics). 4 blocks/bucket, 64 nodes/block, 8 threads/node,
// batch-4 => 32 loads in flight per node, shfl_xor(1)+(2)+(4) combine.
// 20B rows, 4.0MB L2-resident table. nt on streams.
__global__ void __launch_bounds__(512, 8)
p4b_acc_kernel(const int* __restrict__ ebuf,
               const int* __restrict__ nodeoff,
               const int* __restrict__ flag,
               const unsigned* __restrict__ htab,
               const float* __restrict__ disf,
               const float* __restrict__ b_gcn,
               const float* __restrict__ W_fc,
               const float* __restrict__ b_fc,
               float* __restrict__ out) {
    __shared__ float accs[64 * ACCP];    // fallback arm only
    __shared__ float Wfs[F_HID * F_OUT];
    __shared__ float bfs[F_OUT];
    __shared__ float bgs[F_HID];

    int bb = blockIdx.x >> 2;            // bucket
    int q  = blockIdx.x & 3;             // which 64-node quarter
    int t = threadIdx.x;                 // 0..511
    int jl = t >> 3;                     // local node 0..63
    int par = t & 7;                     // lane within node octet
    if (t < F_HID * F_OUT) Wfs[t] = W_fc[t];
    if (t < F_OUT) bfs[t] = b_fc[t];
    if (t < F_HID) bgs[t] = b_gcn[t];
    __syncthreads();

    float* hidden = out;                               // [N, F_HID]
    floatx4* o24 = reinterpret_cast<floatx4*>(out + (long long)N_NODES * F_HID);

    int i = bb * NPB + q * 64 + jl;
    bool valid = (i < N_NODES);
    float acc[F_HID];
#pragma unroll
    for (int f = 0; f < F_HID; ++f) acc[f] = 0.0f;

    if (flag[bb]) {
        // ---------- fast arm: (ld, src-window)-sorted, register accumulation ----------
        int rs = valid ? nodeoff[i] : 0;
        int re = valid ? nodeoff[i + 1] : 0;
        for (int k0 = rs + par; k0 < re; k0 += 32) {   // this thread: k0, k0+8, k0+16, k0+24
            unsigned v[4]; uintx4 qa[4]; unsigned qb[4];
#pragma unroll
            for (int u = 0; u < 4; ++u)
                v[u] = (unsigned)__builtin_nontemporal_load(ebuf + min(k0 + 8 * u, re - 1));
#pragma unroll
            for (int u = 0; u < 4; ++u) {
                const unsigned* r = htab + (long long)(v[u] & 0x3FFFF) * 5;
                qa[u] = *reinterpret_cast<const uintx4_a4*>(r);
                qb[u] = r[4];
            }
#pragma unroll
            for (int u = 0; u < 4; ++u) {
                if (k0 + 8 * u < re) {
                    float2 f01 = up2(qa[u].x), f23 = up2(qa[u].y);
                    float2 f45 = up2(qa[u].z), f67 = up2(qa[u].w);
                    float2 f89 = up2(qb[u]);
                    acc[0] += f01.x; acc[1] += f01.y;
                    acc[2] += f23.x; acc[3] += f23.y;
                    acc[4] += f45.x; acc[5] += f45.y;
                    acc[6] += f67.x; acc[7] += f67.y;
                    acc[8] += f89.x; acc[9] += f89.y;
                }
            }
        }
    } else {
        // ---------- fallback arm: unsorted bucket, LDS atomics (never taken for valid input) ----
        for (int j = t; j < 64 * ACCP; j += blockDim.x) accs[j] = 0.0f;
        __syncthreads();
        int start = nodeoff[bb * NPB];
        int end = (bb < BINS - 1) ? nodeoff[(bb + 1) * NPB] : nodeoff[BINS * NPB];
        for (int e = start + t; e < end; e += blockDim.x) {
            unsigned v = (unsigned)ebuf[e];
            int s = v & 0x3FFFF;
            int ld = v >> 18;
            if ((ld >> 6) != q) continue;              // only this block's quarter
            const unsigned* r = htab + (long long)s * 5;
            uintx4 qa = *reinterpret_cast<const uintx4_a4*>(r);
            unsigned qb = r[4];
            float2 f01 = up2(qa.x), f23 = up2(qa.y), f45 = up2(qa.z), f67 = up2(qa.w), f89 = up2(qb);
            float* a = &accs[(ld - q * 64) * ACCP];
            atomicAdd(a + 0, f01.x); atomicAdd(a + 1, f01.y);
            atomicAdd(a + 2, f23.x); atomicAdd(a + 3, f23.y);
            atomicAdd(a + 4, f45.x); atomicAdd(a + 5, f45.y);
            atomicAdd(a + 6, f67.x); atomicAdd(a + 7, f67.y);
            atomicAdd(a + 8, f89.x); atomicAdd(a + 9, f89.y);
        }
        __syncthreads();
        if (par == 0) {                  // one lane per node takes the LDS sum; others stay 0
#pragma unroll
            for (int f = 0; f < F_HID; ++f) acc[f] = accs[jl * ACCP + f];
        }
    }

    // octet-combine: acc[node] = sum of 8 lanes
#pragma unroll
    for (int f = 0; f < F_HID; ++f) {
        acc[f] += __shfl_xor(acc[f], 1);
        acc[f] += __shfl_xor(acc[f], 2);
        acc[f] += __shfl_xor(acc[f], 4);
    }

    if (!valid || par) return;

    const unsigned* r = htab + (long long)i * 5;
    uintx4 qa = *reinterpret_cast<const uintx4_a4*>(r);
    unsigned qb = r[4];
    float di = disf[i];
    float2 f01 = up2(qa.x), f23 = up2(qa.y), f45 = up2(qa.z), f67 = up2(qa.w), f89 = up2(qb);
    float hp[F_HID] = {f01.x, f01.y, f23.x, f23.y, f45.x, f45.y, f67.x, f67.y, f89.x, f89.y};

    float hv[F_HID];
#pragma unroll
    for (int f = 0; f < F_HID; ++f) {
        hv[f] = (acc[f] + hp[f]) * di + bgs[f];    // (sum_nbrs h' + h'[i]) * dis[i] + b
        __builtin_nontemporal_store(hv[f], hidden + (long long)i * F_HID + f);
    }
    floatx4 o;
#pragma unroll
    for (int jj = 0; jj < F_OUT; ++jj) {
        float vv = bfs[jj];
#pragma unroll
        for (int f = 0; f < F_HID; ++f) vv += hv[f] * Wfs[f * F_OUT + jj];
        o[jj] = fmaxf(vv, 0.0f);
    }
    __builtin_nontemporal_store(o, o24 + i);
}

// ================================================================ FALLBACK (atomic scatter, small ws)
__global__ void fb_init_kernel(const float* __restrict__ x, const float* __restrict__ Wg,
                               float* __restrict__ hpad, float* __restrict__ deg,
                               float* __restrict__ hidden) {
    __shared__ float Ws[F_IN * F_HID];
    for (int t = threadIdx.x; t < F_IN * F_HID; t += blockDim.x) Ws[t] = Wg[t];
    __syncthreads();
    int i = blockIdx.x * blockDim.x + threadIdx.x;
    if (i >= N_NODES) return;
    float acc[F_HID];
#pragma unroll
    for (int f = 0; f < F_HID; ++f) acc[f] = 0.0f;
    const float* xr = x + (long long)i * F_IN;
#pragma unroll
    for (int k = 0; k < F_IN; ++k) {
        float xv = xr[k];
#pragma unroll
        for (int f = 0; f < F_HID; ++f) acc[f] += xv * Ws[k * F_HID + f];
    }
    float* hr = hpad + (long long)i * HPAD;
#pragma unroll
    for (int f = 0; f < F_HID; ++f) hr[f] = acc[f];
    hr[10] = 0.0f; hr[11] = 0.0f;
    deg[i] = 1.0f;
    float* hd = hidden + (long long)i * F_HID;
#pragma unroll
    for (int f = 0; f < F_HID; ++f) hd[f] = 0.0f;
}

__global__ void fb_deg_kernel(const int* __restrict__ ei, const int* __restrict__ mode_p,
                              float* __restrict__ deg) {
    const int mode = *mode_p;
    long long e = (long long)blockIdx.x * blockDim.x + threadIdx.x;
    if (e >= N_EDGES) return;
    int d = load_idx(ei, (long long)N_EDGES + e, mode);
    if ((unsigned)d < (unsigned)N_NODES) atomicAdd(&deg[d], 1.0f);
}

__global__ void fb_scatter_kernel(const int* __restrict__ ei, const int* __restrict__ mode_p,
                                  const float* __restrict__ hpad, const float* __restrict__ deg,
                                  float* __restrict__ hidden) {
    const int mode = *mode_p;
    long long e = (long long)blockIdx.x * blockDim.x + threadIdx.x;
    if (e >= N_EDGES) return;
    int s = load_idx(ei, e, mode);
    int d = load_idx(ei, (long long)N_EDGES + e, mode);
    if ((unsigned)s >= (unsigned)N_NODES || (unsigned)d >= (unsigned)N_NODES) return;
    float norm = rsqrtf(deg[s]) * rsqrtf(deg[d]);
    const float4* h4 = reinterpret_cast<const float4*>(hpad + (long long)s * HPAD);
    float4 a = h4[0]; float4 b = h4[1]; float4 c = h4[2];
    float* o = hidden + (long long)d * F_HID;
    atomicAdd(o + 0, a.x * norm); atomicAdd(o + 1, a.y * norm);
    atomicAdd(o + 2, a.z * norm); atomicAdd(o + 3, a.w * norm);
    atomicAdd(o + 4, b.x * norm); atomicAdd(o + 5, b.y * norm);
    atomicAdd(o + 6, b.z * norm); atomicAdd(o + 7, b.w * norm);
    atomicAdd(o + 8, c.x * norm); atomicAdd(o + 9, c.y * norm);
}

__global__ void fb_finalize_kernel(const float* __restrict__ hpad, const float* __restrict__ deg,
                                   const float* __restrict__ b_gcn, const float* __restrict__ W_fc,
                                   const float* __restrict__ b_fc, float* __restrict__ out) {
    __shared__ float Wf[F_HID * F_OUT];
    __shared__ float bf_s[F_OUT];
    __shared__ float bg_s[F_HID];
    for (int t = threadIdx.x; t < F_HID * F_OUT; t += blockDim.x) Wf[t] = W_fc[t];
    if (threadIdx.x < F_OUT) bf_s[threadIdx.x] = b_fc[threadIdx.x];
    if (threadIdx.x < F_HID) bg_s[threadIdx.x] = b_gcn[threadIdx.x];
    __syncthreads();
    int i = blockIdx.x * blockDim.x + threadIdx.x;
    if (i >= N_NODES) return;
    float* hidden = out;
    float* o2 = out + (long long)N_NODES * F_HID;
    float inv = 1.0f / deg[i];
    const float* hr = hpad + (long long)i * HPAD;
    float* hd = hidden + (long long)i * F_HID;
    float hv[F_HID];
#pragma unroll
    for (int f = 0; f < F_HID; ++f) {
        hv[f] = hd[f] + hr[f] * inv + bg_s[f];
        hd[f] = hv[f];
    }
#pragma unroll
    for (int j = 0; j < F_OUT; ++j) {
        float o = bf_s[j];
#pragma unroll
        for (int f = 0; f < F_HID; ++f) o += hv[f] * Wf[f * F_OUT + j];
        o2[(long long)i * F_OUT + j] = fmaxf(o, 0.0f);
    }
}

// ---------------------------------------------------------------- launch
extern "C" void kernel_launch(void* const* d_in, const int* in_sizes, int n_in,
                              void* d_out, int out_size, void* d_ws, size_t ws_size,
                              hipStream_t stream) {
    const float* x  = (const float*)d_in[0];
    const int*   ei = (const int*)d_in[1];
    const float* Wg = (const float*)d_in[2];
    const float* bg = (const float*)d_in[3];
    const float* Wf = (const float*)d_in[4];
    const float* bf = (const float*)d_in[5];
    float* out = (float*)d_out;

    const int nblk_node = (N_NODES + 255) / 256;     // 782

    // main ws layout (~34 MB)
    unsigned* htab    = (unsigned*)d_ws;                            // N*5 dwords = 4.0MB
    float*    disf    = (float*)(htab + (size_t)N_NODES * 5);       // N
    int*      bcnt    = (int*)(disf + N_NODES);                     // SCAN_L
    int*      boff    = bcnt + SCAN_L;                              // SCAN_L
    int*      bsum    = boff + SCAN_L;                              // 1024 (NA=598 used)
    int*      total   = bsum + 1024;                                // 1
    int*      nodeoff = total + 1;                                  // BINS*NPB+1
    int*      flag    = nodeoff + BINS * NPB + 1;                   // BINS
    int*      ebuf    = flag + BINS;                                // N_EDGES
    int*      mode    = ebuf + N_EDGES;                             // 1
    size_t need = (size_t)((char*)(mode + 1) - (char*)d_ws);

    if (ws_size >= need) {
        detect_mode_kernel<<<1, 64, 0, stream>>>(ei, mode);
        p1_count_kernel<<<BLK1, 1024, 0, stream>>>(ei, mode, bcnt);
        scanA_kernel<<<NA, 512, 0, stream>>>(bcnt, bsum);
        scanB_kernel<<<1, 1024, 0, stream>>>(bsum, total);
        scanC_kernel<<<NA, 512, 0, stream>>>(bcnt, bsum, boff);
        p3_fill_kernel<<<BLK1, 1024, 0, stream>>>(ei, mode, bcnt, boff, ebuf);
        p5_sort_kernel<<<BINS, 1024, 0, stream>>>(ebuf, boff, total, disf, nodeoff, flag);
        init2_kernel<<<nblk_node, 256, 0, stream>>>(x, Wg, disf, htab);
        p4b_acc_kernel<<<BINS * 4, 512, 0, stream>>>(ebuf, nodeoff, flag, htab, disf,
                                                     bg, Wf, bf, out);
    } else {
        // fallback: atomic scatter (~10.4 MB)
        float* hpad  = (float*)d_ws;
        float* degf  = hpad + (size_t)N_NODES * HPAD;
        int*   mode2 = (int*)(degf + N_NODES);
        const int nblk_edge = (N_EDGES + 255) / 256;
        detect_mode_kernel<<<1, 64, 0, stream>>>(ei, mode2);
        fb_init_kernel<<<nblk_node, 256, 0, stream>>>(x, Wg, hpad, degf, out);
        fb_deg_kernel<<<nblk_edge, 256, 0, stream>>>(ei, mode2, degf);
        fb_scatter_kernel<<<nblk_edge, 256, 0, stream>>>(ei, mode2, hpad, degf, out);
        fb_finalize_kernel<<<nblk_node, 256, 0, stream>>>(hpad, degf, bg, Wf, bf, out);
    }
}